// Round 7
// baseline (200.622 us; speedup 1.0000x reference)
//
#include <hip/hip_runtime.h>
#include <hip/hip_bf16.h>
#include <math.h>

#define B 2
#define T 2048
#define C 1024
#define NH 16
#define NKV 4
#define HD 64
#define M 64
#define GC 32
#define S_TOT (M + T)   // 2112
#define EPS 1e-6f

using bf16x8  = __attribute__((ext_vector_type(8))) __bf16;
using f32x4   = __attribute__((ext_vector_type(4))) float;
using ushort8 = __attribute__((ext_vector_type(8))) unsigned short;
using ushort4v= __attribute__((ext_vector_type(4))) unsigned short;

typedef __attribute__((address_space(1))) const void GV;
typedef __attribute__((address_space(3))) void LV;

__device__ inline unsigned short f2bf(float f) {
    __bf16 h = (__bf16)f;
    return __builtin_bit_cast(unsigned short, h);
}
__device__ inline float bf2f(unsigned short u) {
    unsigned int x = (unsigned int)u << 16;
    return __builtin_bit_cast(float, x);
}
__device__ inline float wave_sum(float v) {
    #pragma unroll
    for (int off = 32; off; off >>= 1) v += __shfl_xor(v, off, 64);
    return v;
}

// ------------------------------------------------------------ fp32 -> bf16
__global__ __launch_bounds__(256) void cast_kernel(
    const float* __restrict__ src, unsigned short* __restrict__ dst, int n4)
{
    int i = blockIdx.x * 256 + threadIdx.x;
    if (i < n4) {
        float4 v = ((const float4*)src)[i];
        ushort4v o;
        o.x = f2bf(v.x); o.y = f2bf(v.y); o.z = f2bf(v.z); o.w = f2bf(v.w);
        ((ushort4v*)dst)[i] = o;
    }
}

// ------------------------------------------------------- bf16 MFMA GEMM (m97)
template<bool OUT_BF16>
__global__ __launch_bounds__(256) void gemm_bf16(
    const unsigned short* __restrict__ A, const unsigned short* __restrict__ Bt,
    void* __restrict__ Cc, int Nn, int Kk)
{
    __shared__ unsigned short As[128 * 64];
    __shared__ unsigned short Bs[128 * 64];
    const int tid = threadIdx.x;
    const int w = tid >> 6, lane = tid & 63, lx = lane & 15, hi = lane >> 4;
    const int wr = w >> 1, wc = w & 1;
    const int m0 = blockIdx.y * 128, n0 = blockIdx.x * 128;
    const int lrow = lane >> 3;
    const int lcol = (lane & 7) * 8;

    f32x4 acc[4][4];
    #pragma unroll
    for (int mi = 0; mi < 4; ++mi)
        #pragma unroll
        for (int ni = 0; ni < 4; ++ni) acc[mi][ni] = (f32x4){0.f, 0.f, 0.f, 0.f};

    for (int k0 = 0; k0 < Kk; k0 += 64) {
        #pragma unroll
        for (int p = 0; p < 4; ++p) {
            const int chunk = w * 4 + p;
            const int row = chunk * 8 + lrow;
            __builtin_amdgcn_global_load_lds(
                (GV*)(A + (size_t)(m0 + row) * Kk + k0 + lcol),
                (LV*)(As + chunk * 512), 16, 0, 0);
            __builtin_amdgcn_global_load_lds(
                (GV*)(Bt + (size_t)(n0 + row) * Kk + k0 + lcol),
                (LV*)(Bs + chunk * 512), 16, 0, 0);
        }
        __syncthreads();
        #pragma unroll
        for (int kk = 0; kk < 2; ++kk) {
            bf16x8 af[4], bfr[4];
            #pragma unroll
            for (int mi = 0; mi < 4; ++mi)
                af[mi] = *(const bf16x8*)&As[(wr * 64 + mi * 16 + lx) * 64 + kk * 32 + hi * 8];
            #pragma unroll
            for (int ni = 0; ni < 4; ++ni)
                bfr[ni] = *(const bf16x8*)&Bs[(wc * 64 + ni * 16 + lx) * 64 + kk * 32 + hi * 8];
            #pragma unroll
            for (int mi = 0; mi < 4; ++mi)
                #pragma unroll
                for (int ni = 0; ni < 4; ++ni)
                    acc[mi][ni] = __builtin_amdgcn_mfma_f32_16x16x32_bf16(
                        af[mi], bfr[ni], acc[mi][ni], 0, 0, 0);
        }
        __syncthreads();
    }
    #pragma unroll
    for (int mi = 0; mi < 4; ++mi)
        #pragma unroll
        for (int ni = 0; ni < 4; ++ni)
            #pragma unroll
            for (int r = 0; r < 4; ++r) {
                size_t idx = (size_t)(m0 + wr * 64 + mi * 16 + hi * 4 + r) * Nn
                           + n0 + wc * 64 + ni * 16 + lx;
                if constexpr (OUT_BF16) ((unsigned short*)Cc)[idx] = f2bf(acc[mi][ni][r]);
                else                    ((float*)Cc)[idx] = acc[mi][ni][r];
            }
}

// ------------------------------------------------- gate + RoPE + RMS fusion
// q scale folds 1/sqrt(HD) AND log2(e): 1.2 * 0.125 * 1.44269504 = 0.21640426
__global__ __launch_bounds__(256) void fuse_kernel(
    const float* __restrict__ x, const float* __restrict__ ve,
    const float* __restrict__ cosb, const float* __restrict__ sinb,
    const float* __restrict__ Wg, const unsigned short* __restrict__ qkv,
    unsigned short* __restrict__ qh, unsigned short* __restrict__ kfull,
    unsigned short* __restrict__ vfull)
{
    const int bt = blockIdx.x;
    const int b = bt >> 11, t = bt & (T - 1);
    const int w = threadIdx.x >> 6, l = threadIdx.x & 63, i = l & 31;
    const float c = cosb[t * 32 + i];
    const float s = sinb[t * 32 + i];
    const unsigned short* row = qkv + (size_t)bt * 1536;

    #pragma unroll
    for (int hq = 0; hq < 4; ++hq) {
        const int h = w + hq * 4;
        float x1 = bf2f(row[h * 64 + i]);
        float x2 = bf2f(row[h * 64 + i + 32]);
        float val = (l < 32) ? (x1 * c - x2 * s) : (x1 * s + x2 * c);
        float ss = wave_sum(val * val);
        float scale = rsqrtf(ss * (1.f / 64.f) + EPS) * 0.21640426f;
        qh[((size_t)(b * NH + h) * T + t) * 64 + l] = f2bf(val * scale);
    }
    {
        float x1 = bf2f(row[1024 + w * 64 + i]);
        float x2 = bf2f(row[1024 + w * 64 + i + 32]);
        float val = (l < 32) ? (x1 * c - x2 * s) : (x1 * s + x2 * c);
        float ss = wave_sum(val * val);
        float scale = rsqrtf(ss * (1.f / 64.f) + EPS) * 1.2f;
        kfull[((size_t)(b * NKV + w) * S_TOT + M + t) * 64 + l] = f2bf(val * scale);
    }
    {
        const float* xr = x + (size_t)bt * 1024;
        float g = 0.f;
        #pragma unroll
        for (int gi = 0; gi < GC; ++gi) g += xr[gi] * Wg[w * GC + gi];
        g = 3.f / (1.f + __expf(-g));
        float vv = bf2f(row[1280 + w * 64 + l]) + g * ve[(size_t)bt * 256 + w * 64 + l];
        vfull[((size_t)(b * NKV + w) * S_TOT + M + t) * 64 + l] = f2bf(vv);
    }
}

// ------------------------------------------------------- memory token prep
__global__ __launch_bounds__(256) void mem_kernel(
    const float* __restrict__ mem_k, const float* __restrict__ mem_v,
    const float* __restrict__ vscal,
    unsigned short* __restrict__ kfull, unsigned short* __restrict__ vfull)
{
    const int bm = blockIdx.x;
    const int b = bm >> 6, mr = bm & 63;
    const int w = threadIdx.x >> 6, l = threadIdx.x & 63;
    const size_t src = ((size_t)mr * NKV + w) * HD + l;
    float kvv = mem_k[src];
    float ss = wave_sum(kvv * kvv);
    float scale = rsqrtf(ss * (1.f / 64.f) + EPS) * 1.2f;
    const size_t dst = ((size_t)(b * NKV + w) * S_TOT + mr) * 64 + l;
    kfull[dst] = f2bf(kvv * scale);
    vfull[dst] = f2bf(mem_v[src] * vscal[0]);
}

// --------------------------------------------------------- MFMA flash attn v7
// block = (tt, h, b): 128 q-rows, 8 waves x 16 rows, 512 threads.
// K: async global_load_lds dbuf (ONE call per wave: 8 waves x 8 rows = 64),
// XOR-swizzled source; V: reg-prefetch -> swizzled transposed LDS dbuf;
// Ps swizzled. 1 barrier/tile. exp2 domain. Wave-uniform mask specialization.
struct AttnShared {
    unsigned short Ks[2][4096];   // [buf][row*64 + swz-col]  (K[s][d])
    unsigned short Vt[2][4096];   // [buf][row*64 + swz-col]  (V^T[d][s])
    unsigned short Ps[128 * 64];  // [row*64 + swz-col]       (P[t][s])
};

__device__ __forceinline__ void attn_tile(
    const int st, const int nst, const int lastw, const int t0w, const int w,
    const int lane, const int lx, const int hi,
    const unsigned short* __restrict__ kbase,
    const unsigned short* __restrict__ vbase,
    AttnShared* sh, ushort8& vn_c, ushort8& vn_n,
    const bf16x8 (&aq)[2],
    f32x4 (&o_acc)[4], float (&m_r)[4], float (&l_r)[4])
{
    const int cur = st & 1;
    // 1. write prefetched V (tile st) transposed+swizzled into Vt[cur]
    #pragma unroll
    for (int j = 0; j < 8; ++j) {
        const int row = w * 8 + j;                     // d index
        sh->Vt[cur][row * 64 + ((((lane >> 3) ^ (row & 7)) << 3) | (lane & 7))] =
            (unsigned short)vn_c[j];
    }
    __syncthreads();   // drains K gload_lds for tile st; publishes Vt[cur]
    // 2. prefetch tile st+1 (8 waves x 8 rows = full 64-row K tile)
    if (st + 1 < nst) {
        const int s0n = (st + 1) * 64;
        const int swz = ((lane & 7) ^ (lane >> 3)) << 3;
        __builtin_amdgcn_global_load_lds(
            (GV*)(kbase + (size_t)(s0n + w * 8 + (lane >> 3)) * 64 + swz),
            (LV*)(&sh->Ks[cur ^ 1][w * 512]), 16, 0, 0);
        vn_n = *(const ushort8*)&vbase[(size_t)(s0n + lane) * 64 + w * 8];
    }
    if (st > lastw) return;   // fully masked for this wave: staging+barrier only
    // 3. K fragments (swizzled read)
    const int r7 = lx & 7;
    bf16x8 kb0[4], kb1[4];
    #pragma unroll
    for (int nt = 0; nt < 4; ++nt) {
        const int row = nt * 16 + lx;
        kb0[nt] = *(const bf16x8*)&sh->Ks[cur][row * 64 + ((hi ^ r7) << 3)];
        kb1[nt] = *(const bf16x8*)&sh->Ks[cur][row * 64 + (((4 + hi) ^ r7) << 3)];
    }
    // 4. S = Q K^T (log2e and 1/sqrt(d) folded into q)
    f32x4 s_acc[4];
    #pragma unroll
    for (int nt = 0; nt < 4; ++nt) {
        s_acc[nt] = (f32x4){0.f, 0.f, 0.f, 0.f};
        s_acc[nt] = __builtin_amdgcn_mfma_f32_16x16x32_bf16(aq[0], kb0[nt], s_acc[nt], 0, 0, 0);
        s_acc[nt] = __builtin_amdgcn_mfma_f32_16x16x32_bf16(aq[1], kb1[nt], s_acc[nt], 0, 0, 0);
    }
    // 5. mask (diag tile only) + online softmax in exp2 domain
    if (st == lastw) {
        #pragma unroll
        for (int r = 0; r < 4; ++r) {
            const int thr = t0w + hi * 4 + r + 64 - 64 * st;
            #pragma unroll
            for (int nt = 0; nt < 4; ++nt)
                if (nt * 16 + lx > thr) s_acc[nt][r] = -INFINITY;
        }
    }
    float mx[4];
    #pragma unroll
    for (int r = 0; r < 4; ++r)
        mx[r] = fmaxf(fmaxf(s_acc[0][r], s_acc[1][r]), fmaxf(s_acc[2][r], s_acc[3][r]));
    #pragma unroll
    for (int off = 1; off < 16; off <<= 1)
        #pragma unroll
        for (int r = 0; r < 4; ++r) mx[r] = fmaxf(mx[r], __shfl_xor(mx[r], off, 64));
    #pragma unroll
    for (int r = 0; r < 4; ++r) {
        const float mn = fmaxf(m_r[r], mx[r]);
        const float resc = exp2f(m_r[r] - mn);
        m_r[r] = mn;
        float ps = 0.f;
        const int prow = w * 16 + hi * 4 + r;
        #pragma unroll
        for (int nt = 0; nt < 4; ++nt) {
            float p = exp2f(s_acc[nt][r] - mn);
            ps += p;
            sh->Ps[prow * 64 + ((((nt * 2 + (lx >> 3)) ^ (prow & 7)) << 3) | (lx & 7))] = f2bf(p);
        }
        l_r[r] = l_r[r] * resc + ps;
        #pragma unroll
        for (int dt = 0; dt < 4; ++dt) o_acc[dt][r] *= resc;
    }
    // 6. O += P V  (Ps rows wave-private; same-wave LDS ops are ordered)
    #pragma unroll
    for (int kk = 0; kk < 2; ++kk) {
        const int parow = w * 16 + lx;
        bf16x8 pa = *(const bf16x8*)&sh->Ps[parow * 64 + (((kk * 4 + hi) ^ r7) << 3)];
        #pragma unroll
        for (int dt = 0; dt < 4; ++dt) {
            const int vrow = dt * 16 + lx;
            bf16x8 vb = *(const bf16x8*)&sh->Vt[cur][vrow * 64 + (((kk * 4 + hi) ^ r7) << 3)];
            o_acc[dt] = __builtin_amdgcn_mfma_f32_16x16x32_bf16(pa, vb, o_acc[dt], 0, 0, 0);
        }
    }
}

__global__ __launch_bounds__(512) void attn_kernel(
    const unsigned short* __restrict__ qh, const unsigned short* __restrict__ kf,
    const unsigned short* __restrict__ vf, unsigned short* __restrict__ y)
{
    __shared__ AttnShared sh;
    const int tt = (T / 128 - 1) - blockIdx.x;   // long blocks launch first
    const int h = blockIdx.y, b = blockIdx.z;
    const int kv = h >> 2, t0 = tt * 128;
    const int tid = threadIdx.x, w = tid >> 6, lane = tid & 63;
    const int lx = lane & 15, hi = lane >> 4;
    const int t0w = t0 + 16 * w;              // wave's first q row
    const int lastw = (t0w >> 6) + 1;         // this wave's diagonal tile

    bf16x8 aq[2];
    {
        const unsigned short* qp = qh + ((size_t)(b * NH + h) * T + t0w + lx) * 64;
        aq[0] = *(const bf16x8*)&qp[hi * 8];
        aq[1] = *(const bf16x8*)&qp[32 + hi * 8];
    }
    f32x4 o_acc[4];
    float m_r[4], l_r[4];
    #pragma unroll
    for (int dt = 0; dt < 4; ++dt) o_acc[dt] = (f32x4){0.f, 0.f, 0.f, 0.f};
    #pragma unroll
    for (int r = 0; r < 4; ++r) { m_r[r] = -INFINITY; l_r[r] = 0.f; }

    const unsigned short* kbase = kf + (size_t)(b * NKV + kv) * S_TOT * 64;
    const unsigned short* vbase = vf + (size_t)(b * NKV + kv) * S_TOT * 64;

    const int nst = 2 * tt + 3;   // always odd
    // prologue: stage K tile 0 -> Ks[0] (one call per wave); V tile 0 -> regs
    {
        const int swz = ((lane & 7) ^ (lane >> 3)) << 3;
        __builtin_amdgcn_global_load_lds(
            (GV*)(kbase + (size_t)(w * 8 + (lane >> 3)) * 64 + swz),
            (LV*)(&sh.Ks[0][w * 512]), 16, 0, 0);
    }
    ushort8 vnA, vnB;
    vnA = *(const ushort8*)&vbase[(size_t)lane * 64 + w * 8];
    for (int st = 0; st < nst; st += 2) {
        attn_tile(st, nst, lastw, t0w, w, lane, lx, hi, kbase, vbase, &sh,
                  vnA, vnB, aq, o_acc, m_r, l_r);
        if (st + 1 < nst)
            attn_tile(st + 1, nst, lastw, t0w, w, lane, lx, hi, kbase, vbase, &sh,
                      vnB, vnA, aq, o_acc, m_r, l_r);
    }

    float lt[4];
    #pragma unroll
    for (int r = 0; r < 4; ++r) {
        float v = l_r[r];
        #pragma unroll
        for (int off = 1; off < 16; off <<= 1) v += __shfl_xor(v, off, 64);
        lt[r] = 1.f / v;
    }
    #pragma unroll
    for (int dt = 0; dt < 4; ++dt)
        #pragma unroll
        for (int r = 0; r < 4; ++r) {
            int t = t0w + hi * 4 + r;
            y[((size_t)(b * T) + t) * 1024 + h * 64 + dt * 16 + lx] =
                f2bf(o_acc[dt][r] * lt[r]);
        }
}

// ----------------------------------------------------------------- launcher
extern "C" void kernel_launch(void* const* d_in, const int* in_sizes, int n_in,
                              void* d_out, int out_size, void* d_ws, size_t ws_size,
                              hipStream_t stream)
{
    const float* x     = (const float*)d_in[0];
    const float* ve    = (const float*)d_in[1];
    const float* cosb  = (const float*)d_in[2];
    const float* sinb  = (const float*)d_in[3];
    const float* Wq    = (const float*)d_in[4];
    const float* Wk    = (const float*)d_in[5];
    const float* Wv    = (const float*)d_in[6];
    const float* Wproj = (const float*)d_in[7];
    const float* Wg    = (const float*)d_in[8];
    const float* memk  = (const float*)d_in[9];
    const float* memv  = (const float*)d_in[10];
    const float* vscal = (const float*)d_in[11];

    unsigned short* xh    = (unsigned short*)d_ws;
    unsigned short* wqkv  = xh + (size_t)4096 * 1024;
    unsigned short* wproj = wqkv + (size_t)1536 * 1024;
    unsigned short* qhb   = wproj + (size_t)1024 * 1024;
    unsigned short* kfull = qhb + (size_t)4096 * 1024;
    unsigned short* vfull = kfull + (size_t)B * NKV * S_TOT * 64;
    unsigned short* qkvb  = vfull + (size_t)B * NKV * S_TOT * 64;
    unsigned short* ybuf  = xh;   // alias: xh dead after QKV GEMM
    float* out = (float*)d_out;

    const dim3 blk(256);
    cast_kernel<<<dim3(4096), blk, 0, stream>>>(x, xh, 1048576);
    cast_kernel<<<dim3(1024), blk, 0, stream>>>(Wq, wqkv, 262144);
    cast_kernel<<<dim3(256),  blk, 0, stream>>>(Wk, wqkv + (size_t)1024 * 1024, 65536);
    cast_kernel<<<dim3(256),  blk, 0, stream>>>(Wv, wqkv + (size_t)1280 * 1024, 65536);
    cast_kernel<<<dim3(1024), blk, 0, stream>>>(Wproj, wproj, 262144);

    gemm_bf16<true><<<dim3(12, 32), blk, 0, stream>>>(xh, wqkv, qkvb, 1536, 1024);
    fuse_kernel<<<dim3(B * T), blk, 0, stream>>>(x, ve, cosb, sinb, Wg, qkvb,
                                                 qhb, kfull, vfull);
    mem_kernel<<<dim3(B * M), blk, 0, stream>>>(memk, memv, vscal, kfull, vfull);
    attn_kernel<<<dim3(T / 128, NH, B), dim3(512), 0, stream>>>(qhb, kfull, vfull, ybuf);
    gemm_bf16<false><<<dim3(8, 32), blk, 0, stream>>>(ybuf, wproj, out, 1024, 1024);
}

// Round 8
// 155.371 us; speedup vs baseline: 1.2912x; 1.2912x over previous
//
#include <hip/hip_runtime.h>
#include <hip/hip_bf16.h>
#include <math.h>

#define B 2
#define T 2048
#define C 1024
#define NH 16
#define NKV 4
#define HD 64
#define M 64
#define GC 32
#define S_TOT (M + T)   // 2112
#define EPS 1e-6f

using bf16x8  = __attribute__((ext_vector_type(8))) __bf16;
using f32x4   = __attribute__((ext_vector_type(4))) float;
using ushort8 = __attribute__((ext_vector_type(8))) unsigned short;
using ushort4v= __attribute__((ext_vector_type(4))) unsigned short;

typedef __attribute__((address_space(1))) const void GV;
typedef __attribute__((address_space(3))) void LV;

__device__ inline unsigned short f2bf(float f) {
    __bf16 h = (__bf16)f;
    return __builtin_bit_cast(unsigned short, h);
}
__device__ inline float bf2f(unsigned short u) {
    unsigned int x = (unsigned int)u << 16;
    return __builtin_bit_cast(float, x);
}
__device__ inline float wave_sum(float v) {
    #pragma unroll
    for (int off = 32; off; off >>= 1) v += __shfl_xor(v, off, 64);
    return v;
}

// ------------------------------------------------------------ fp32 -> bf16
__global__ __launch_bounds__(256) void cast_kernel(
    const float* __restrict__ src, unsigned short* __restrict__ dst, int n4)
{
    int i = blockIdx.x * 256 + threadIdx.x;
    if (i < n4) {
        float4 v = ((const float4*)src)[i];
        ushort4v o;
        o.x = f2bf(v.x); o.y = f2bf(v.y); o.z = f2bf(v.z); o.w = f2bf(v.w);
        ((ushort4v*)dst)[i] = o;
    }
}

// ------------------------------------------------------- bf16 MFMA GEMM (m97)
template<bool OUT_BF16>
__global__ __launch_bounds__(256) void gemm_bf16(
    const unsigned short* __restrict__ A, const unsigned short* __restrict__ Bt,
    void* __restrict__ Cc, int Nn, int Kk)
{
    __shared__ unsigned short As[128 * 64];
    __shared__ unsigned short Bs[128 * 64];
    const int tid = threadIdx.x;
    const int w = tid >> 6, lane = tid & 63, lx = lane & 15, hi = lane >> 4;
    const int wr = w >> 1, wc = w & 1;
    const int m0 = blockIdx.y * 128, n0 = blockIdx.x * 128;
    const int lrow = lane >> 3;
    const int lcol = (lane & 7) * 8;

    f32x4 acc[4][4];
    #pragma unroll
    for (int mi = 0; mi < 4; ++mi)
        #pragma unroll
        for (int ni = 0; ni < 4; ++ni) acc[mi][ni] = (f32x4){0.f, 0.f, 0.f, 0.f};

    for (int k0 = 0; k0 < Kk; k0 += 64) {
        #pragma unroll
        for (int p = 0; p < 4; ++p) {
            const int chunk = w * 4 + p;
            const int row = chunk * 8 + lrow;
            __builtin_amdgcn_global_load_lds(
                (GV*)(A + (size_t)(m0 + row) * Kk + k0 + lcol),
                (LV*)(As + chunk * 512), 16, 0, 0);
            __builtin_amdgcn_global_load_lds(
                (GV*)(Bt + (size_t)(n0 + row) * Kk + k0 + lcol),
                (LV*)(Bs + chunk * 512), 16, 0, 0);
        }
        __syncthreads();
        #pragma unroll
        for (int kk = 0; kk < 2; ++kk) {
            bf16x8 af[4], bfr[4];
            #pragma unroll
            for (int mi = 0; mi < 4; ++mi)
                af[mi] = *(const bf16x8*)&As[(wr * 64 + mi * 16 + lx) * 64 + kk * 32 + hi * 8];
            #pragma unroll
            for (int ni = 0; ni < 4; ++ni)
                bfr[ni] = *(const bf16x8*)&Bs[(wc * 64 + ni * 16 + lx) * 64 + kk * 32 + hi * 8];
            #pragma unroll
            for (int mi = 0; mi < 4; ++mi)
                #pragma unroll
                for (int ni = 0; ni < 4; ++ni)
                    acc[mi][ni] = __builtin_amdgcn_mfma_f32_16x16x32_bf16(
                        af[mi], bfr[ni], acc[mi][ni], 0, 0, 0);
        }
        __syncthreads();
    }
    #pragma unroll
    for (int mi = 0; mi < 4; ++mi)
        #pragma unroll
        for (int ni = 0; ni < 4; ++ni)
            #pragma unroll
            for (int r = 0; r < 4; ++r) {
                size_t idx = (size_t)(m0 + wr * 64 + mi * 16 + hi * 4 + r) * Nn
                           + n0 + wc * 64 + ni * 16 + lx;
                if constexpr (OUT_BF16) ((unsigned short*)Cc)[idx] = f2bf(acc[mi][ni][r]);
                else                    ((float*)Cc)[idx] = acc[mi][ni][r];
            }
}

// ------------------------------------------------- gate + RoPE + RMS fusion
// q scale folds 1/sqrt(HD) AND log2(e): 1.2 * 0.125 * 1.44269504 = 0.21640426
__global__ __launch_bounds__(256) void fuse_kernel(
    const float* __restrict__ x, const float* __restrict__ ve,
    const float* __restrict__ cosb, const float* __restrict__ sinb,
    const float* __restrict__ Wg, const unsigned short* __restrict__ qkv,
    unsigned short* __restrict__ qh, unsigned short* __restrict__ kfull,
    unsigned short* __restrict__ vfull)
{
    const int bt = blockIdx.x;
    const int b = bt >> 11, t = bt & (T - 1);
    const int w = threadIdx.x >> 6, l = threadIdx.x & 63, i = l & 31;
    const float c = cosb[t * 32 + i];
    const float s = sinb[t * 32 + i];
    const unsigned short* row = qkv + (size_t)bt * 1536;

    #pragma unroll
    for (int hq = 0; hq < 4; ++hq) {
        const int h = w + hq * 4;
        float x1 = bf2f(row[h * 64 + i]);
        float x2 = bf2f(row[h * 64 + i + 32]);
        float val = (l < 32) ? (x1 * c - x2 * s) : (x1 * s + x2 * c);
        float ss = wave_sum(val * val);
        float scale = rsqrtf(ss * (1.f / 64.f) + EPS) * 0.21640426f;
        qh[((size_t)(b * NH + h) * T + t) * 64 + l] = f2bf(val * scale);
    }
    {
        float x1 = bf2f(row[1024 + w * 64 + i]);
        float x2 = bf2f(row[1024 + w * 64 + i + 32]);
        float val = (l < 32) ? (x1 * c - x2 * s) : (x1 * s + x2 * c);
        float ss = wave_sum(val * val);
        float scale = rsqrtf(ss * (1.f / 64.f) + EPS) * 1.2f;
        kfull[((size_t)(b * NKV + w) * S_TOT + M + t) * 64 + l] = f2bf(val * scale);
    }
    {
        const float* xr = x + (size_t)bt * 1024;
        float g = 0.f;
        #pragma unroll
        for (int gi = 0; gi < GC; ++gi) g += xr[gi] * Wg[w * GC + gi];
        g = 3.f / (1.f + __expf(-g));
        float vv = bf2f(row[1280 + w * 64 + l]) + g * ve[(size_t)bt * 256 + w * 64 + l];
        vfull[((size_t)(b * NKV + w) * S_TOT + M + t) * 64 + l] = f2bf(vv);
    }
}

// ------------------------------------------------------- memory token prep
__global__ __launch_bounds__(256) void mem_kernel(
    const float* __restrict__ mem_k, const float* __restrict__ mem_v,
    const float* __restrict__ vscal,
    unsigned short* __restrict__ kfull, unsigned short* __restrict__ vfull)
{
    const int bm = blockIdx.x;
    const int b = bm >> 6, mr = bm & 63;
    const int w = threadIdx.x >> 6, l = threadIdx.x & 63;
    const size_t src = ((size_t)mr * NKV + w) * HD + l;
    float kvv = mem_k[src];
    float ss = wave_sum(kvv * kvv);
    float scale = rsqrtf(ss * (1.f / 64.f) + EPS) * 1.2f;
    const size_t dst = ((size_t)(b * NKV + w) * S_TOT + mr) * 64 + l;
    kfull[dst] = f2bf(kvv * scale);
    vfull[dst] = f2bf(mem_v[src] * vscal[0]);
}

// --------------------------------------------------------- MFMA flash attn v8
// Causal pairing: block (p, h, b) owns q-tiles jA=p and jB=31-p (64 rows each),
// which share their s-prefix. Each staged s-tile is computed against B always
// and A while st <= jA+1 -> uniform 35 compute-tiles/wave across ALL blocks.
// 4 waves x 16 q-rows per q-tile. K: async gload_lds dbuf (swizzled source);
// V: reg-prefetch -> swizzled transposed LDS dbuf; Ps swizzled; exp2 domain.
struct AttnShared {
    unsigned short Ks[2][4096];   // [buf][row*64 + swz-col]  (K[s][d])
    unsigned short Vt[2][4096];   // [buf][row*64 + swz-col]  (V^T[d][s])
    unsigned short Ps[64 * 64];   // [row*64 + swz-col]       (P[t][s])
};

__device__ __forceinline__ void attn_compute(
    const bool diag, const int trel,   // diag-threshold base = 16w+hi*4
    const int w, const int lx, const int hi, const int r7, const int cur,
    AttnShared* sh, const bf16x8 (&kb0)[4], const bf16x8 (&kb1)[4],
    const bf16x8 (&aq)[2],
    f32x4 (&o_acc)[4], float (&m_r)[4], float (&l_r)[4])
{
    // S = Q K^T (log2e and 1/sqrt(d) folded into q)
    f32x4 s_acc[4];
    #pragma unroll
    for (int nt = 0; nt < 4; ++nt) {
        s_acc[nt] = (f32x4){0.f, 0.f, 0.f, 0.f};
        s_acc[nt] = __builtin_amdgcn_mfma_f32_16x16x32_bf16(aq[0], kb0[nt], s_acc[nt], 0, 0, 0);
        s_acc[nt] = __builtin_amdgcn_mfma_f32_16x16x32_bf16(aq[1], kb1[nt], s_acc[nt], 0, 0, 0);
    }
    if (diag) {
        #pragma unroll
        for (int r = 0; r < 4; ++r) {
            const int thr = trel + r;
            #pragma unroll
            for (int nt = 0; nt < 4; ++nt)
                if (nt * 16 + lx > thr) s_acc[nt][r] = -INFINITY;
        }
    }
    float mx[4];
    #pragma unroll
    for (int r = 0; r < 4; ++r)
        mx[r] = fmaxf(fmaxf(s_acc[0][r], s_acc[1][r]), fmaxf(s_acc[2][r], s_acc[3][r]));
    #pragma unroll
    for (int off = 1; off < 16; off <<= 1)
        #pragma unroll
        for (int r = 0; r < 4; ++r) mx[r] = fmaxf(mx[r], __shfl_xor(mx[r], off, 64));
    #pragma unroll
    for (int r = 0; r < 4; ++r) {
        const float mn = fmaxf(m_r[r], mx[r]);
        const float resc = exp2f(m_r[r] - mn);
        m_r[r] = mn;
        float ps = 0.f;
        const int prow = w * 16 + hi * 4 + r;
        #pragma unroll
        for (int nt = 0; nt < 4; ++nt) {
            float p = exp2f(s_acc[nt][r] - mn);
            ps += p;
            sh->Ps[prow * 64 + ((((nt * 2 + (lx >> 3)) ^ (prow & 7)) << 3) | (lx & 7))] = f2bf(p);
        }
        l_r[r] = l_r[r] * resc + ps;
        #pragma unroll
        for (int dt = 0; dt < 4; ++dt) o_acc[dt][r] *= resc;
    }
    // O += P V   (Ps rows wave-private; same-wave LDS ops ordered)
    #pragma unroll
    for (int kk = 0; kk < 2; ++kk) {
        bf16x8 pa = *(const bf16x8*)&sh->Ps[(w * 16 + lx) * 64 + (((kk * 4 + hi) ^ r7) << 3)];
        #pragma unroll
        for (int dt = 0; dt < 4; ++dt) {
            bf16x8 vb = *(const bf16x8*)&sh->Vt[cur][(dt * 16 + lx) * 64 + (((kk * 4 + hi) ^ r7) << 3)];
            o_acc[dt] = __builtin_amdgcn_mfma_f32_16x16x32_bf16(pa, vb, o_acc[dt], 0, 0, 0);
        }
    }
}

__device__ __forceinline__ void attn_tile(
    const int st, const int nst, const int lastA, const int w,
    const int lane, const int lx, const int hi,
    const unsigned short* __restrict__ kbase,
    const unsigned short* __restrict__ vbase,
    AttnShared* sh, ushort8 (&vn_c)[2], ushort8 (&vn_n)[2],
    const bf16x8 (&aqA)[2], const bf16x8 (&aqB)[2],
    f32x4 (&oA)[4], float (&mA)[4], float (&lA)[4],
    f32x4 (&oB)[4], float (&mB)[4], float (&lB)[4])
{
    const int cur = st & 1;
    const int r7 = lx & 7;
    // 1. write prefetched V (tile st) transposed+swizzled into Vt[cur]
    #pragma unroll
    for (int p = 0; p < 2; ++p)
        #pragma unroll
        for (int j = 0; j < 8; ++j) {
            const int row = w * 16 + p * 8 + j;    // d index
            sh->Vt[cur][row * 64 + ((((lane >> 3) ^ (row & 7)) << 3) | (lane & 7))] =
                (unsigned short)vn_c[p][j];
        }
    __syncthreads();   // drains K gload_lds for tile st; publishes Vt[cur]
    // 2. prefetch tile st+1 (4 waves x 2 chunks x 8 rows = 64-row K tile)
    if (st + 1 < nst) {
        const int s0n = (st + 1) * 64;
        const int swz = ((lane & 7) ^ (lane >> 3)) << 3;
        #pragma unroll
        for (int p = 0; p < 2; ++p) {
            const int chunk = w * 2 + p;
            __builtin_amdgcn_global_load_lds(
                (GV*)(kbase + (size_t)(s0n + chunk * 8 + (lane >> 3)) * 64 + swz),
                (LV*)(&sh->Ks[cur ^ 1][chunk * 512]), 16, 0, 0);
        }
        const unsigned short* vp = vbase + (size_t)(s0n + lane) * 64 + w * 16;
        vn_n[0] = *(const ushort8*)&vp[0];
        vn_n[1] = *(const ushort8*)&vp[8];
    }
    // 3. K fragments (swizzled read), shared by both q-tiles
    bf16x8 kb0[4], kb1[4];
    #pragma unroll
    for (int nt = 0; nt < 4; ++nt) {
        const int row = nt * 16 + lx;
        kb0[nt] = *(const bf16x8*)&sh->Ks[cur][row * 64 + ((hi ^ r7) << 3)];
        kb1[nt] = *(const bf16x8*)&sh->Ks[cur][row * 64 + (((4 + hi) ^ r7) << 3)];
    }
    const int trel = 16 * w + hi * 4;
    // 4. compute: B every tile; A while st <= lastA
    attn_compute(st == nst - 1, trel, w, lx, hi, r7, cur, sh, kb0, kb1, aqB, oB, mB, lB);
    if (st <= lastA)
        attn_compute(st == lastA, trel, w, lx, hi, r7, cur, sh, kb0, kb1, aqA, oA, mA, lA);
}

__global__ __launch_bounds__(256) void attn_kernel(
    const unsigned short* __restrict__ qh, const unsigned short* __restrict__ kf,
    const unsigned short* __restrict__ vf, unsigned short* __restrict__ y)
{
    __shared__ AttnShared sh;
    const int p = blockIdx.x;                  // pair index 0..15
    const int h = blockIdx.y, b = blockIdx.z;
    const int kv = h >> 2;
    const int jA = p, jB = 31 - p;
    const int t0A = jA * 64, t0B = jB * 64;
    const int tid = threadIdx.x, w = tid >> 6, lane = tid & 63;
    const int lx = lane & 15, hi = lane >> 4;

    bf16x8 aqA[2], aqB[2];
    {
        const unsigned short* qp = qh + ((size_t)(b * NH + h) * T + t0A + 16 * w + lx) * 64;
        aqA[0] = *(const bf16x8*)&qp[hi * 8];
        aqA[1] = *(const bf16x8*)&qp[32 + hi * 8];
        const unsigned short* qb = qh + ((size_t)(b * NH + h) * T + t0B + 16 * w + lx) * 64;
        aqB[0] = *(const bf16x8*)&qb[hi * 8];
        aqB[1] = *(const bf16x8*)&qb[32 + hi * 8];
    }
    f32x4 oA[4], oB[4];
    float mA[4], lA[4], mB[4], lB[4];
    #pragma unroll
    for (int dt = 0; dt < 4; ++dt) {
        oA[dt] = (f32x4){0.f, 0.f, 0.f, 0.f};
        oB[dt] = (f32x4){0.f, 0.f, 0.f, 0.f};
    }
    #pragma unroll
    for (int r = 0; r < 4; ++r) {
        mA[r] = -INFINITY; lA[r] = 0.f;
        mB[r] = -INFINITY; lB[r] = 0.f;
    }

    const unsigned short* kbase = kf + (size_t)(b * NKV + kv) * S_TOT * 64;
    const unsigned short* vbase = vf + (size_t)(b * NKV + kv) * S_TOT * 64;

    const int nst = jB + 2;          // 18..33
    const int lastA = jA + 1;
    // prologue: stage K tile 0 -> Ks[0]; V tile 0 -> regs
    {
        const int swz = ((lane & 7) ^ (lane >> 3)) << 3;
        #pragma unroll
        for (int q = 0; q < 2; ++q) {
            const int chunk = w * 2 + q;
            __builtin_amdgcn_global_load_lds(
                (GV*)(kbase + (size_t)(chunk * 8 + (lane >> 3)) * 64 + swz),
                (LV*)(&sh.Ks[0][chunk * 512]), 16, 0, 0);
        }
    }
    ushort8 vnA[2], vnB[2];
    {
        const unsigned short* vp = vbase + (size_t)lane * 64 + w * 16;
        vnA[0] = *(const ushort8*)&vp[0];
        vnA[1] = *(const ushort8*)&vp[8];
    }
    for (int st = 0; st < nst; st += 2) {
        attn_tile(st, nst, lastA, w, lane, lx, hi, kbase, vbase, &sh,
                  vnA, vnB, aqA, aqB, oA, mA, lA, oB, mB, lB);
        if (st + 1 < nst)
            attn_tile(st + 1, nst, lastA, w, lane, lx, hi, kbase, vbase, &sh,
                      vnB, vnA, aqA, aqB, oA, mA, lA, oB, mB, lB);
    }

    // epilogue: l-reduce + write both q-tiles
    #pragma unroll
    for (int qi = 0; qi < 2; ++qi) {
        const int t0 = qi ? t0B : t0A;
        f32x4* o = qi ? oB : oA;
        float* l_r = qi ? lB : lA;
        float lt[4];
        #pragma unroll
        for (int r = 0; r < 4; ++r) {
            float v = l_r[r];
            #pragma unroll
            for (int off = 1; off < 16; off <<= 1) v += __shfl_xor(v, off, 64);
            lt[r] = 1.f / v;
        }
        #pragma unroll
        for (int dt = 0; dt < 4; ++dt)
            #pragma unroll
            for (int r = 0; r < 4; ++r) {
                int t = t0 + 16 * w + hi * 4 + r;
                y[((size_t)(b * T) + t) * 1024 + h * 64 + dt * 16 + lx] =
                    f2bf(o[dt][r] * lt[r]);
            }
    }
}

// ----------------------------------------------------------------- launcher
extern "C" void kernel_launch(void* const* d_in, const int* in_sizes, int n_in,
                              void* d_out, int out_size, void* d_ws, size_t ws_size,
                              hipStream_t stream)
{
    const float* x     = (const float*)d_in[0];
    const float* ve    = (const float*)d_in[1];
    const float* cosb  = (const float*)d_in[2];
    const float* sinb  = (const float*)d_in[3];
    const float* Wq    = (const float*)d_in[4];
    const float* Wk    = (const float*)d_in[5];
    const float* Wv    = (const float*)d_in[6];
    const float* Wproj = (const float*)d_in[7];
    const float* Wg    = (const float*)d_in[8];
    const float* memk  = (const float*)d_in[9];
    const float* memv  = (const float*)d_in[10];
    const float* vscal = (const float*)d_in[11];

    unsigned short* xh    = (unsigned short*)d_ws;
    unsigned short* wqkv  = xh + (size_t)4096 * 1024;
    unsigned short* wproj = wqkv + (size_t)1536 * 1024;
    unsigned short* qhb   = wproj + (size_t)1024 * 1024;
    unsigned short* kfull = qhb + (size_t)4096 * 1024;
    unsigned short* vfull = kfull + (size_t)B * NKV * S_TOT * 64;
    unsigned short* qkvb  = vfull + (size_t)B * NKV * S_TOT * 64;
    unsigned short* ybuf  = xh;   // alias: xh dead after QKV GEMM
    float* out = (float*)d_out;

    const dim3 blk(256);
    cast_kernel<<<dim3(4096), blk, 0, stream>>>(x, xh, 1048576);
    cast_kernel<<<dim3(1024), blk, 0, stream>>>(Wq, wqkv, 262144);
    cast_kernel<<<dim3(256),  blk, 0, stream>>>(Wk, wqkv + (size_t)1024 * 1024, 65536);
    cast_kernel<<<dim3(256),  blk, 0, stream>>>(Wv, wqkv + (size_t)1280 * 1024, 65536);
    cast_kernel<<<dim3(1024), blk, 0, stream>>>(Wproj, wproj, 262144);

    gemm_bf16<true><<<dim3(12, 32), blk, 0, stream>>>(xh, wqkv, qkvb, 1536, 1024);
    fuse_kernel<<<dim3(B * T), blk, 0, stream>>>(x, ve, cosb, sinb, Wg, qkvb,
                                                 qhb, kfull, vfull);
    mem_kernel<<<dim3(B * M), blk, 0, stream>>>(memk, memv, vscal, kfull, vfull);
    attn_kernel<<<dim3(16, NH, B), blk, 0, stream>>>(qhb, kfull, vfull, ybuf);
    gemm_bf16<false><<<dim3(8, 32), blk, 0, stream>>>(ybuf, wproj, out, 1024, 1024);
}

// Round 9
// 128.798 us; speedup vs baseline: 1.5577x; 1.2063x over previous
//
#include <hip/hip_runtime.h>
#include <hip/hip_bf16.h>
#include <math.h>

#define B 2
#define T 2048
#define C 1024
#define NH 16
#define NKV 4
#define HD 64
#define M 64
#define GC 32
#define S_TOT (M + T)   // 2112
#define EPS 1e-6f
// |score| bound in exp2 domain: ||q||*||k|| = (8*0.2164)*(8*1.2) = 16.62
#define FIXED_MAX 17.0f

using bf16x8  = __attribute__((ext_vector_type(8))) __bf16;
using f32x4   = __attribute__((ext_vector_type(4))) float;
using ushort8 = __attribute__((ext_vector_type(8))) unsigned short;
using ushort4v= __attribute__((ext_vector_type(4))) unsigned short;

typedef __attribute__((address_space(1))) const void GV;
typedef __attribute__((address_space(3))) void LV;

__device__ inline unsigned short f2bf(float f) {
    __bf16 h = (__bf16)f;
    return __builtin_bit_cast(unsigned short, h);
}
__device__ inline float bf2f(unsigned short u) {
    unsigned int x = (unsigned int)u << 16;
    return __builtin_bit_cast(float, x);
}
__device__ inline float wave_sum(float v) {
    #pragma unroll
    for (int off = 32; off; off >>= 1) v += __shfl_xor(v, off, 64);
    return v;
}

// ----------------------------------------- fused fp32 -> bf16 (all 5 inputs)
// dst segments are contiguous in ws: x | Wq | Wk | Wv | Wproj
__global__ __launch_bounds__(256) void cast_all(
    const float* __restrict__ s0, const float* __restrict__ s1,
    const float* __restrict__ s2, const float* __restrict__ s3,
    const float* __restrict__ s4, unsigned short* __restrict__ dst)
{
    const int i = blockIdx.x * 256 + threadIdx.x;   // float4 index, 1703936 total
    const float* src; int off;
    if      (i < 1048576) { src = s0; off = i; }
    else if (i < 1310720) { src = s1; off = i - 1048576; }
    else if (i < 1376256) { src = s2; off = i - 1310720; }
    else if (i < 1441792) { src = s3; off = i - 1376256; }
    else                  { src = s4; off = i - 1441792; }
    float4 v = ((const float4*)src)[off];
    ushort4v o;
    o.x = f2bf(v.x); o.y = f2bf(v.y); o.z = f2bf(v.z); o.w = f2bf(v.w);
    ((ushort4v*)dst)[i] = o;
}

// ------------------------------------------------------- bf16 MFMA GEMM (m97)
template<bool OUT_BF16>
__global__ __launch_bounds__(256) void gemm_bf16(
    const unsigned short* __restrict__ A, const unsigned short* __restrict__ Bt,
    void* __restrict__ Cc, int Nn, int Kk)
{
    __shared__ unsigned short As[128 * 64];
    __shared__ unsigned short Bs[128 * 64];
    const int tid = threadIdx.x;
    const int w = tid >> 6, lane = tid & 63, lx = lane & 15, hi = lane >> 4;
    const int wr = w >> 1, wc = w & 1;
    const int m0 = blockIdx.y * 128, n0 = blockIdx.x * 128;
    const int lrow = lane >> 3;
    const int lcol = (lane & 7) * 8;

    f32x4 acc[4][4];
    #pragma unroll
    for (int mi = 0; mi < 4; ++mi)
        #pragma unroll
        for (int ni = 0; ni < 4; ++ni) acc[mi][ni] = (f32x4){0.f, 0.f, 0.f, 0.f};

    for (int k0 = 0; k0 < Kk; k0 += 64) {
        #pragma unroll
        for (int p = 0; p < 4; ++p) {
            const int chunk = w * 4 + p;
            const int row = chunk * 8 + lrow;
            __builtin_amdgcn_global_load_lds(
                (GV*)(A + (size_t)(m0 + row) * Kk + k0 + lcol),
                (LV*)(As + chunk * 512), 16, 0, 0);
            __builtin_amdgcn_global_load_lds(
                (GV*)(Bt + (size_t)(n0 + row) * Kk + k0 + lcol),
                (LV*)(Bs + chunk * 512), 16, 0, 0);
        }
        __syncthreads();
        #pragma unroll
        for (int kk = 0; kk < 2; ++kk) {
            bf16x8 af[4], bfr[4];
            #pragma unroll
            for (int mi = 0; mi < 4; ++mi)
                af[mi] = *(const bf16x8*)&As[(wr * 64 + mi * 16 + lx) * 64 + kk * 32 + hi * 8];
            #pragma unroll
            for (int ni = 0; ni < 4; ++ni)
                bfr[ni] = *(const bf16x8*)&Bs[(wc * 64 + ni * 16 + lx) * 64 + kk * 32 + hi * 8];
            #pragma unroll
            for (int mi = 0; mi < 4; ++mi)
                #pragma unroll
                for (int ni = 0; ni < 4; ++ni)
                    acc[mi][ni] = __builtin_amdgcn_mfma_f32_16x16x32_bf16(
                        af[mi], bfr[ni], acc[mi][ni], 0, 0, 0);
        }
        __syncthreads();
    }
    #pragma unroll
    for (int mi = 0; mi < 4; ++mi)
        #pragma unroll
        for (int ni = 0; ni < 4; ++ni)
            #pragma unroll
            for (int r = 0; r < 4; ++r) {
                size_t idx = (size_t)(m0 + wr * 64 + mi * 16 + hi * 4 + r) * Nn
                           + n0 + wc * 64 + ni * 16 + lx;
                if constexpr (OUT_BF16) ((unsigned short*)Cc)[idx] = f2bf(acc[mi][ni][r]);
                else                    ((float*)Cc)[idx] = acc[mi][ni][r];
            }
}

// ------------------------------------------------- gate + RoPE + RMS fusion
// q scale folds 1/sqrt(HD) AND log2(e): 1.2 * 0.125 * 1.44269504 = 0.21640426
__global__ __launch_bounds__(256) void fuse_kernel(
    const float* __restrict__ x, const float* __restrict__ ve,
    const float* __restrict__ cosb, const float* __restrict__ sinb,
    const float* __restrict__ Wg, const unsigned short* __restrict__ qkv,
    unsigned short* __restrict__ qh, unsigned short* __restrict__ kfull,
    unsigned short* __restrict__ vfull)
{
    const int bt = blockIdx.x;
    const int b = bt >> 11, t = bt & (T - 1);
    const int w = threadIdx.x >> 6, l = threadIdx.x & 63, i = l & 31;
    const float c = cosb[t * 32 + i];
    const float s = sinb[t * 32 + i];
    const unsigned short* row = qkv + (size_t)bt * 1536;

    #pragma unroll
    for (int hq = 0; hq < 4; ++hq) {
        const int h = w + hq * 4;
        float x1 = bf2f(row[h * 64 + i]);
        float x2 = bf2f(row[h * 64 + i + 32]);
        float val = (l < 32) ? (x1 * c - x2 * s) : (x1 * s + x2 * c);
        float ss = wave_sum(val * val);
        float scale = rsqrtf(ss * (1.f / 64.f) + EPS) * 0.21640426f;
        qh[((size_t)(b * NH + h) * T + t) * 64 + l] = f2bf(val * scale);
    }
    {
        float x1 = bf2f(row[1024 + w * 64 + i]);
        float x2 = bf2f(row[1024 + w * 64 + i + 32]);
        float val = (l < 32) ? (x1 * c - x2 * s) : (x1 * s + x2 * c);
        float ss = wave_sum(val * val);
        float scale = rsqrtf(ss * (1.f / 64.f) + EPS) * 1.2f;
        kfull[((size_t)(b * NKV + w) * S_TOT + M + t) * 64 + l] = f2bf(val * scale);
    }
    {
        const float* xr = x + (size_t)bt * 1024;
        float g = 0.f;
        #pragma unroll
        for (int gi = 0; gi < GC; ++gi) g += xr[gi] * Wg[w * GC + gi];
        g = 3.f / (1.f + __expf(-g));
        float vv = bf2f(row[1280 + w * 64 + l]) + g * ve[(size_t)bt * 256 + w * 64 + l];
        vfull[((size_t)(b * NKV + w) * S_TOT + M + t) * 64 + l] = f2bf(vv);
    }
}

// ------------------------------------------------------- memory token prep
__global__ __launch_bounds__(256) void mem_kernel(
    const float* __restrict__ mem_k, const float* __restrict__ mem_v,
    const float* __restrict__ vscal,
    unsigned short* __restrict__ kfull, unsigned short* __restrict__ vfull)
{
    const int bm = blockIdx.x;
    const int b = bm >> 6, mr = bm & 63;
    const int w = threadIdx.x >> 6, l = threadIdx.x & 63;
    const size_t src = ((size_t)mr * NKV + w) * HD + l;
    float kvv = mem_k[src];
    float ss = wave_sum(kvv * kvv);
    float scale = rsqrtf(ss * (1.f / 64.f) + EPS) * 1.2f;
    const size_t dst = ((size_t)(b * NKV + w) * S_TOT + mr) * 64 + l;
    kfull[dst] = f2bf(kvv * scale);
    vfull[dst] = f2bf(mem_v[src] * vscal[0]);
}

// --------------------------------------------------------- MFMA flash attn v9
// Causal pairing (R8 structure) + FIXED-MAX softmax: RMS-normalized q,k bound
// |score| <= 16.62 in exp2 domain, so p = exp2(s - 17) needs NO online max,
// NO rescale, NO cross-lane reduce. l is a plain accumulate.
struct AttnShared {
    unsigned short Ks[2][4096];   // [buf][row*64 + swz-col]  (K[s][d])
    unsigned short Vt[2][4096];   // [buf][row*64 + swz-col]  (V^T[d][s])
    unsigned short Ps[64 * 64];   // [row*64 + swz-col]       (P[t][s])
};

__device__ __forceinline__ void attn_compute(
    const bool diag, const int trel,
    const int w, const int lx, const int hi, const int r7, const int cur,
    AttnShared* sh, const bf16x8 (&kb0)[4], const bf16x8 (&kb1)[4],
    const bf16x8 (&aq)[2],
    f32x4 (&o_acc)[4], float (&l_r)[4])
{
    // S = Q K^T (log2e and 1/sqrt(d) folded into q)
    f32x4 s_acc[4];
    #pragma unroll
    for (int nt = 0; nt < 4; ++nt) {
        s_acc[nt] = (f32x4){0.f, 0.f, 0.f, 0.f};
        s_acc[nt] = __builtin_amdgcn_mfma_f32_16x16x32_bf16(aq[0], kb0[nt], s_acc[nt], 0, 0, 0);
        s_acc[nt] = __builtin_amdgcn_mfma_f32_16x16x32_bf16(aq[1], kb1[nt], s_acc[nt], 0, 0, 0);
    }
    if (diag) {
        #pragma unroll
        for (int r = 0; r < 4; ++r) {
            const int thr = trel + r;
            #pragma unroll
            for (int nt = 0; nt < 4; ++nt)
                if (nt * 16 + lx > thr) s_acc[nt][r] = -INFINITY;
        }
    }
    // fixed-shift exp2; plain accumulate of l; P -> swizzled LDS
    #pragma unroll
    for (int r = 0; r < 4; ++r) {
        float ps = 0.f;
        const int prow = w * 16 + hi * 4 + r;
        #pragma unroll
        for (int nt = 0; nt < 4; ++nt) {
            float p = exp2f(s_acc[nt][r] - FIXED_MAX);
            ps += p;
            sh->Ps[prow * 64 + ((((nt * 2 + (lx >> 3)) ^ (prow & 7)) << 3) | (lx & 7))] = f2bf(p);
        }
        l_r[r] += ps;
    }
    // O += P V   (Ps rows wave-private; same-wave LDS ops ordered)
    #pragma unroll
    for (int kk = 0; kk < 2; ++kk) {
        bf16x8 pa = *(const bf16x8*)&sh->Ps[(w * 16 + lx) * 64 + (((kk * 4 + hi) ^ r7) << 3)];
        #pragma unroll
        for (int dt = 0; dt < 4; ++dt) {
            bf16x8 vb = *(const bf16x8*)&sh->Vt[cur][(dt * 16 + lx) * 64 + (((kk * 4 + hi) ^ r7) << 3)];
            o_acc[dt] = __builtin_amdgcn_mfma_f32_16x16x32_bf16(pa, vb, o_acc[dt], 0, 0, 0);
        }
    }
}

__device__ __forceinline__ void attn_tile(
    const int st, const int nst, const int lastA, const int w,
    const int lane, const int lx, const int hi,
    const unsigned short* __restrict__ kbase,
    const unsigned short* __restrict__ vbase,
    AttnShared* sh, ushort8 (&vn_c)[2], ushort8 (&vn_n)[2],
    const bf16x8 (&aqA)[2], const bf16x8 (&aqB)[2],
    f32x4 (&oA)[4], float (&lA)[4],
    f32x4 (&oB)[4], float (&lB)[4])
{
    const int cur = st & 1;
    const int r7 = lx & 7;
    // 1. write prefetched V (tile st) transposed+swizzled into Vt[cur]
    #pragma unroll
    for (int p = 0; p < 2; ++p)
        #pragma unroll
        for (int j = 0; j < 8; ++j) {
            const int row = w * 16 + p * 8 + j;    // d index
            sh->Vt[cur][row * 64 + ((((lane >> 3) ^ (row & 7)) << 3) | (lane & 7))] =
                (unsigned short)vn_c[p][j];
        }
    __syncthreads();   // drains K gload_lds for tile st; publishes Vt[cur]
    // 2. prefetch tile st+1
    if (st + 1 < nst) {
        const int s0n = (st + 1) * 64;
        const int swz = ((lane & 7) ^ (lane >> 3)) << 3;
        #pragma unroll
        for (int p = 0; p < 2; ++p) {
            const int chunk = w * 2 + p;
            __builtin_amdgcn_global_load_lds(
                (GV*)(kbase + (size_t)(s0n + chunk * 8 + (lane >> 3)) * 64 + swz),
                (LV*)(&sh->Ks[cur ^ 1][chunk * 512]), 16, 0, 0);
        }
        const unsigned short* vp = vbase + (size_t)(s0n + lane) * 64 + w * 16;
        vn_n[0] = *(const ushort8*)&vp[0];
        vn_n[1] = *(const ushort8*)&vp[8];
    }
    // 3. K fragments (swizzled read), shared by both q-tiles
    bf16x8 kb0[4], kb1[4];
    #pragma unroll
    for (int nt = 0; nt < 4; ++nt) {
        const int row = nt * 16 + lx;
        kb0[nt] = *(const bf16x8*)&sh->Ks[cur][row * 64 + ((hi ^ r7) << 3)];
        kb1[nt] = *(const bf16x8*)&sh->Ks[cur][row * 64 + (((4 + hi) ^ r7) << 3)];
    }
    const int trel = 16 * w + hi * 4;
    // 4. compute: B every tile; A while st <= lastA
    attn_compute(st == nst - 1, trel, w, lx, hi, r7, cur, sh, kb0, kb1, aqB, oB, lB);
    if (st <= lastA)
        attn_compute(st == lastA, trel, w, lx, hi, r7, cur, sh, kb0, kb1, aqA, oA, lA);
}

__global__ __launch_bounds__(256) void attn_kernel(
    const unsigned short* __restrict__ qh, const unsigned short* __restrict__ kf,
    const unsigned short* __restrict__ vf, unsigned short* __restrict__ y)
{
    __shared__ AttnShared sh;
    const int p = blockIdx.x;                  // pair index 0..15
    const int h = blockIdx.y, b = blockIdx.z;
    const int kv = h >> 2;
    const int jA = p, jB = 31 - p;
    const int t0A = jA * 64, t0B = jB * 64;
    const int tid = threadIdx.x, w = tid >> 6, lane = tid & 63;
    const int lx = lane & 15, hi = lane >> 4;

    bf16x8 aqA[2], aqB[2];
    {
        const unsigned short* qp = qh + ((size_t)(b * NH + h) * T + t0A + 16 * w + lx) * 64;
        aqA[0] = *(const bf16x8*)&qp[hi * 8];
        aqA[1] = *(const bf16x8*)&qp[32 + hi * 8];
        const unsigned short* qb = qh + ((size_t)(b * NH + h) * T + t0B + 16 * w + lx) * 64;
        aqB[0] = *(const bf16x8*)&qb[hi * 8];
        aqB[1] = *(const bf16x8*)&qb[32 + hi * 8];
    }
    f32x4 oA[4], oB[4];
    float lA[4], lB[4];
    #pragma unroll
    for (int dt = 0; dt < 4; ++dt) {
        oA[dt] = (f32x4){0.f, 0.f, 0.f, 0.f};
        oB[dt] = (f32x4){0.f, 0.f, 0.f, 0.f};
    }
    #pragma unroll
    for (int r = 0; r < 4; ++r) { lA[r] = 0.f; lB[r] = 0.f; }

    const unsigned short* kbase = kf + (size_t)(b * NKV + kv) * S_TOT * 64;
    const unsigned short* vbase = vf + (size_t)(b * NKV + kv) * S_TOT * 64;

    const int nst = jB + 2;          // 18..33
    const int lastA = jA + 1;
    // prologue: stage K tile 0 -> Ks[0]; V tile 0 -> regs
    {
        const int swz = ((lane & 7) ^ (lane >> 3)) << 3;
        #pragma unroll
        for (int q = 0; q < 2; ++q) {
            const int chunk = w * 2 + q;
            __builtin_amdgcn_global_load_lds(
                (GV*)(kbase + (size_t)(chunk * 8 + (lane >> 3)) * 64 + swz),
                (LV*)(&sh.Ks[0][chunk * 512]), 16, 0, 0);
        }
    }
    ushort8 vnA[2], vnB[2];
    {
        const unsigned short* vp = vbase + (size_t)lane * 64 + w * 16;
        vnA[0] = *(const ushort8*)&vp[0];
        vnA[1] = *(const ushort8*)&vp[8];
    }
    for (int st = 0; st < nst; st += 2) {
        attn_tile(st, nst, lastA, w, lane, lx, hi, kbase, vbase, &sh,
                  vnA, vnB, aqA, aqB, oA, lA, oB, lB);
        if (st + 1 < nst)
            attn_tile(st + 1, nst, lastA, w, lane, lx, hi, kbase, vbase, &sh,
                      vnB, vnA, aqA, aqB, oA, lA, oB, lB);
    }

    // epilogue: l-reduce + write both q-tiles
    #pragma unroll
    for (int qi = 0; qi < 2; ++qi) {
        const int t0 = qi ? t0B : t0A;
        f32x4* o = qi ? oB : oA;
        float* l_r = qi ? lB : lA;
        float lt[4];
        #pragma unroll
        for (int r = 0; r < 4; ++r) {
            float v = l_r[r];
            #pragma unroll
            for (int off = 1; off < 16; off <<= 1) v += __shfl_xor(v, off, 64);
            lt[r] = 1.f / v;
        }
        #pragma unroll
        for (int dt = 0; dt < 4; ++dt)
            #pragma unroll
            for (int r = 0; r < 4; ++r) {
                int t = t0 + 16 * w + hi * 4 + r;
                y[((size_t)(b * T) + t) * 1024 + h * 64 + dt * 16 + lx] =
                    f2bf(o[dt][r] * lt[r]);
            }
    }
}

// ----------------------------------------------------------------- launcher
extern "C" void kernel_launch(void* const* d_in, const int* in_sizes, int n_in,
                              void* d_out, int out_size, void* d_ws, size_t ws_size,
                              hipStream_t stream)
{
    const float* x     = (const float*)d_in[0];
    const float* ve    = (const float*)d_in[1];
    const float* cosb  = (const float*)d_in[2];
    const float* sinb  = (const float*)d_in[3];
    const float* Wq    = (const float*)d_in[4];
    const float* Wk    = (const float*)d_in[5];
    const float* Wv    = (const float*)d_in[6];
    const float* Wproj = (const float*)d_in[7];
    const float* Wg    = (const float*)d_in[8];
    const float* memk  = (const float*)d_in[9];
    const float* memv  = (const float*)d_in[10];
    const float* vscal = (const float*)d_in[11];

    unsigned short* xh    = (unsigned short*)d_ws;
    unsigned short* wqkv  = xh + (size_t)4096 * 1024;
    unsigned short* wproj = wqkv + (size_t)1536 * 1024;
    unsigned short* qhb   = wproj + (size_t)1024 * 1024;
    unsigned short* kfull = qhb + (size_t)4096 * 1024;
    unsigned short* vfull = kfull + (size_t)B * NKV * S_TOT * 64;
    unsigned short* qkvb  = vfull + (size_t)B * NKV * S_TOT * 64;
    unsigned short* ybuf  = xh;   // alias: xh dead after QKV GEMM
    float* out = (float*)d_out;

    const dim3 blk(256);
    // one fused cast: x | Wq | Wk | Wv | Wproj -> contiguous bf16 region at ws
    cast_all<<<dim3(6656), blk, 0, stream>>>(x, Wq, Wk, Wv, Wproj, xh);

    gemm_bf16<true><<<dim3(12, 32), blk, 0, stream>>>(xh, wqkv, qkvb, 1536, 1024);
    fuse_kernel<<<dim3(B * T), blk, 0, stream>>>(x, ve, cosb, sinb, Wg, qkvb,
                                                 qhb, kfull, vfull);
    mem_kernel<<<dim3(B * M), blk, 0, stream>>>(memk, memv, vscal, kfull, vfull);
    attn_kernel<<<dim3(16, NH, B), blk, 0, stream>>>(qhb, kfull, vfull, ybuf);
    gemm_bf16<false><<<dim3(8, 32), blk, 0, stream>>>(ybuf, wproj, out, 1024, 1024);
}

// Round 10
// 114.900 us; speedup vs baseline: 1.7461x; 1.1210x over previous
//
#include <hip/hip_runtime.h>
#include <hip/hip_bf16.h>
#include <math.h>

#define B 2
#define T 2048
#define C 1024
#define NH 16
#define NKV 4
#define HD 64
#define M 64
#define GC 32
#define S_TOT (M + T)   // 2112
#define EPS 1e-6f
// |score| bound in exp2 domain: ||q||*||k|| = (8*0.2164)*(8*1.2) = 16.62
#define FIXED_MAX 17.0f

using bf16x8  = __attribute__((ext_vector_type(8))) __bf16;
using f32x4   = __attribute__((ext_vector_type(4))) float;
using ushort8 = __attribute__((ext_vector_type(8))) unsigned short;
using ushort4v= __attribute__((ext_vector_type(4))) unsigned short;

typedef __attribute__((address_space(1))) const void GV;
typedef __attribute__((address_space(3))) void LV;

__device__ inline unsigned short f2bf(float f) {
    __bf16 h = (__bf16)f;
    return __builtin_bit_cast(unsigned short, h);
}
__device__ inline float bf2f(unsigned short u) {
    unsigned int x = (unsigned int)u << 16;
    return __builtin_bit_cast(float, x);
}
__device__ inline float wave_sum(float v) {
    #pragma unroll
    for (int off = 32; off; off >>= 1) v += __shfl_xor(v, off, 64);
    return v;
}
__device__ __forceinline__ float exp2_raw(float x) {
    float y;
    asm("v_exp_f32 %0, %1" : "=v"(y) : "v"(x));
    return y;
}
__device__ __forceinline__ unsigned int cvt_pk_bf16(float lo, float hi) {
    unsigned int u;
    asm("v_cvt_pk_bf16_f32 %0, %1, %2" : "=v"(u) : "v"(lo), "v"(hi));
    return u;
}

// ----------------------------------------- fused fp32 -> bf16 (all 5 inputs)
__global__ __launch_bounds__(256) void cast_all(
    const float* __restrict__ s0, const float* __restrict__ s1,
    const float* __restrict__ s2, const float* __restrict__ s3,
    const float* __restrict__ s4, unsigned short* __restrict__ dst)
{
    const int i = blockIdx.x * 256 + threadIdx.x;   // float4 index, 1703936 total
    const float* src; int off;
    if      (i < 1048576) { src = s0; off = i; }
    else if (i < 1310720) { src = s1; off = i - 1048576; }
    else if (i < 1376256) { src = s2; off = i - 1310720; }
    else if (i < 1441792) { src = s3; off = i - 1376256; }
    else                  { src = s4; off = i - 1441792; }
    float4 v = ((const float4*)src)[off];
    ushort4v o;
    o.x = f2bf(v.x); o.y = f2bf(v.y); o.z = f2bf(v.z); o.w = f2bf(v.w);
    ((ushort4v*)dst)[i] = o;
}

// ------------------------------------------------------- bf16 MFMA GEMM (m97)
template<bool OUT_BF16>
__global__ __launch_bounds__(256) void gemm_bf16(
    const unsigned short* __restrict__ A, const unsigned short* __restrict__ Bt,
    void* __restrict__ Cc, int Nn, int Kk)
{
    __shared__ unsigned short As[128 * 64];
    __shared__ unsigned short Bs[128 * 64];
    const int tid = threadIdx.x;
    const int w = tid >> 6, lane = tid & 63, lx = lane & 15, hi = lane >> 4;
    const int wr = w >> 1, wc = w & 1;
    const int m0 = blockIdx.y * 128, n0 = blockIdx.x * 128;
    const int lrow = lane >> 3;
    const int lcol = (lane & 7) * 8;

    f32x4 acc[4][4];
    #pragma unroll
    for (int mi = 0; mi < 4; ++mi)
        #pragma unroll
        for (int ni = 0; ni < 4; ++ni) acc[mi][ni] = (f32x4){0.f, 0.f, 0.f, 0.f};

    for (int k0 = 0; k0 < Kk; k0 += 64) {
        #pragma unroll
        for (int p = 0; p < 4; ++p) {
            const int chunk = w * 4 + p;
            const int row = chunk * 8 + lrow;
            __builtin_amdgcn_global_load_lds(
                (GV*)(A + (size_t)(m0 + row) * Kk + k0 + lcol),
                (LV*)(As + chunk * 512), 16, 0, 0);
            __builtin_amdgcn_global_load_lds(
                (GV*)(Bt + (size_t)(n0 + row) * Kk + k0 + lcol),
                (LV*)(Bs + chunk * 512), 16, 0, 0);
        }
        __syncthreads();
        #pragma unroll
        for (int kk = 0; kk < 2; ++kk) {
            bf16x8 af[4], bfr[4];
            #pragma unroll
            for (int mi = 0; mi < 4; ++mi)
                af[mi] = *(const bf16x8*)&As[(wr * 64 + mi * 16 + lx) * 64 + kk * 32 + hi * 8];
            #pragma unroll
            for (int ni = 0; ni < 4; ++ni)
                bfr[ni] = *(const bf16x8*)&Bs[(wc * 64 + ni * 16 + lx) * 64 + kk * 32 + hi * 8];
            #pragma unroll
            for (int mi = 0; mi < 4; ++mi)
                #pragma unroll
                for (int ni = 0; ni < 4; ++ni)
                    acc[mi][ni] = __builtin_amdgcn_mfma_f32_16x16x32_bf16(
                        af[mi], bfr[ni], acc[mi][ni], 0, 0, 0);
        }
        __syncthreads();
    }
    #pragma unroll
    for (int mi = 0; mi < 4; ++mi)
        #pragma unroll
        for (int ni = 0; ni < 4; ++ni)
            #pragma unroll
            for (int r = 0; r < 4; ++r) {
                size_t idx = (size_t)(m0 + wr * 64 + mi * 16 + hi * 4 + r) * Nn
                           + n0 + wc * 64 + ni * 16 + lx;
                if constexpr (OUT_BF16) ((unsigned short*)Cc)[idx] = f2bf(acc[mi][ni][r]);
                else                    ((float*)Cc)[idx] = acc[mi][ni][r];
            }
}

// ------------------------------------------------- gate + RoPE + RMS fusion
// q scale folds 1/sqrt(HD) AND log2(e): 1.2 * 0.125 * 1.44269504 = 0.21640426
__global__ __launch_bounds__(256) void fuse_kernel(
    const float* __restrict__ x, const float* __restrict__ ve,
    const float* __restrict__ cosb, const float* __restrict__ sinb,
    const float* __restrict__ Wg, const unsigned short* __restrict__ qkv,
    unsigned short* __restrict__ qh, unsigned short* __restrict__ kfull,
    unsigned short* __restrict__ vfull)
{
    const int bt = blockIdx.x;
    const int b = bt >> 11, t = bt & (T - 1);
    const int w = threadIdx.x >> 6, l = threadIdx.x & 63, i = l & 31;
    const float c = cosb[t * 32 + i];
    const float s = sinb[t * 32 + i];
    const unsigned short* row = qkv + (size_t)bt * 1536;

    #pragma unroll
    for (int hq = 0; hq < 4; ++hq) {
        const int h = w + hq * 4;
        float x1 = bf2f(row[h * 64 + i]);
        float x2 = bf2f(row[h * 64 + i + 32]);
        float val = (l < 32) ? (x1 * c - x2 * s) : (x1 * s + x2 * c);
        float ss = wave_sum(val * val);
        float scale = rsqrtf(ss * (1.f / 64.f) + EPS) * 0.21640426f;
        qh[((size_t)(b * NH + h) * T + t) * 64 + l] = f2bf(val * scale);
    }
    {
        float x1 = bf2f(row[1024 + w * 64 + i]);
        float x2 = bf2f(row[1024 + w * 64 + i + 32]);
        float val = (l < 32) ? (x1 * c - x2 * s) : (x1 * s + x2 * c);
        float ss = wave_sum(val * val);
        float scale = rsqrtf(ss * (1.f / 64.f) + EPS) * 1.2f;
        kfull[((size_t)(b * NKV + w) * S_TOT + M + t) * 64 + l] = f2bf(val * scale);
    }
    {
        const float* xr = x + (size_t)bt * 1024;
        float g = 0.f;
        #pragma unroll
        for (int gi = 0; gi < GC; ++gi) g += xr[gi] * Wg[w * GC + gi];
        g = 3.f / (1.f + __expf(-g));
        float vv = bf2f(row[1280 + w * 64 + l]) + g * ve[(size_t)bt * 256 + w * 64 + l];
        vfull[((size_t)(b * NKV + w) * S_TOT + M + t) * 64 + l] = f2bf(vv);
    }
}

// ------------------------------------------------------- memory token prep
__global__ __launch_bounds__(256) void mem_kernel(
    const float* __restrict__ mem_k, const float* __restrict__ mem_v,
    const float* __restrict__ vscal,
    unsigned short* __restrict__ kfull, unsigned short* __restrict__ vfull)
{
    const int bm = blockIdx.x;
    const int b = bm >> 6, mr = bm & 63;
    const int w = threadIdx.x >> 6, l = threadIdx.x & 63;
    const size_t src = ((size_t)mr * NKV + w) * HD + l;
    float kvv = mem_k[src];
    float ss = wave_sum(kvv * kvv);
    float scale = rsqrtf(ss * (1.f / 64.f) + EPS) * 1.2f;
    const size_t dst = ((size_t)(b * NKV + w) * S_TOT + mr) * 64 + l;
    kfull[dst] = f2bf(kvv * scale);
    vfull[dst] = f2bf(mem_v[src] * vscal[0]);
}

// -------------------------------------------------------- MFMA flash attn v10
// R9 structure + s-axis pack-permutation sigma(s) = (s&15)*4 + (s>>4) applied
// to BOTH P and V storage (PV invariant): each lane's 4 P-values become one
// contiguous 8B pack -> 2x v_cvt_pk_bf16_f32 + 1x ds_write_b64 per r.
// QK^T accumulator init = -FIXED_MAX (shift rides through MFMA C-in).
struct AttnShared {
    unsigned short Ks[2][4096];   // [buf][row*64 + swz-col]  (K[s][d])
    unsigned short Vt[2][4096];   // [buf][row*64 + swz(sigma(s))]  (V^T[d][q])
    unsigned short Ps[64 * 64];   // [row*64 + swz(q)]        (P[t][q])
};

__device__ __forceinline__ void attn_compute(
    const bool diag, const int trel,
    const int w, const int lx, const int hi, const int r7, const int cur,
    AttnShared* sh, const bf16x8 (&kb0)[4], const bf16x8 (&kb1)[4],
    const bf16x8 (&aq)[2],
    f32x4 (&o_acc)[4], float (&l_r)[4])
{
    // S = Q K^T - FIXED_MAX (shift folded into C-init)
    f32x4 s_acc[4];
    #pragma unroll
    for (int nt = 0; nt < 4; ++nt) {
        s_acc[nt] = (f32x4){-FIXED_MAX, -FIXED_MAX, -FIXED_MAX, -FIXED_MAX};
        s_acc[nt] = __builtin_amdgcn_mfma_f32_16x16x32_bf16(aq[0], kb0[nt], s_acc[nt], 0, 0, 0);
        s_acc[nt] = __builtin_amdgcn_mfma_f32_16x16x32_bf16(aq[1], kb1[nt], s_acc[nt], 0, 0, 0);
    }
    if (diag) {
        #pragma unroll
        for (int r = 0; r < 4; ++r) {
            const int thr = trel + r;
            #pragma unroll
            for (int nt = 0; nt < 4; ++nt)
                if (nt * 16 + lx > thr) s_acc[nt][r] = -INFINITY;
        }
    }
    // exp2 (bare v_exp_f32) + packed bf16 store: q-positions lx*4+nt
    #pragma unroll
    for (int r = 0; r < 4; ++r) {
        const int prow = w * 16 + hi * 4 + r;
        const float p0 = exp2_raw(s_acc[0][r]);
        const float p1 = exp2_raw(s_acc[1][r]);
        const float p2 = exp2_raw(s_acc[2][r]);
        const float p3 = exp2_raw(s_acc[3][r]);
        l_r[r] += (p0 + p1) + (p2 + p3);
        uint2 pk;
        pk.x = cvt_pk_bf16(p0, p1);
        pk.y = cvt_pk_bf16(p2, p3);
        const int idx = prow * 64 + ((((lx >> 1) ^ (prow & 7)) << 3) | ((lx & 1) << 2));
        *(uint2*)&sh->Ps[idx] = pk;   // 8B-aligned
    }
    // O += P V   (read addressing unchanged: group-XOR with r7)
    #pragma unroll
    for (int kk = 0; kk < 2; ++kk) {
        bf16x8 pa = *(const bf16x8*)&sh->Ps[(w * 16 + lx) * 64 + (((kk * 4 + hi) ^ r7) << 3)];
        #pragma unroll
        for (int dt = 0; dt < 4; ++dt) {
            bf16x8 vb = *(const bf16x8*)&sh->Vt[cur][(dt * 16 + lx) * 64 + (((kk * 4 + hi) ^ r7) << 3)];
            o_acc[dt] = __builtin_amdgcn_mfma_f32_16x16x32_bf16(pa, vb, o_acc[dt], 0, 0, 0);
        }
    }
}

__device__ __forceinline__ void attn_tile(
    const int st, const int nst, const int lastA, const int w,
    const int lane, const int lx, const int hi,
    const unsigned short* __restrict__ kbase,
    const unsigned short* __restrict__ vbase,
    AttnShared* sh, ushort8 (&vn_c)[2], ushort8 (&vn_n)[2],
    const bf16x8 (&aqA)[2], const bf16x8 (&aqB)[2],
    f32x4 (&oA)[4], float (&lA)[4],
    f32x4 (&oB)[4], float (&lB)[4])
{
    const int cur = st & 1;
    const int r7 = lx & 7;
    // 1. write prefetched V (tile st) into Vt[cur] at sigma-permuted column
    const int q = (lane & 15) * 4 + (lane >> 4);   // sigma(s), s = lane
    #pragma unroll
    for (int p = 0; p < 2; ++p)
        #pragma unroll
        for (int j = 0; j < 8; ++j) {
            const int row = w * 16 + p * 8 + j;    // d index
            sh->Vt[cur][row * 64 + ((((q >> 3) ^ (row & 7)) << 3) | (q & 7))] =
                (unsigned short)vn_c[p][j];
        }
    __syncthreads();   // drains K gload_lds for tile st; publishes Vt[cur]
    // 2. prefetch tile st+1
    if (st + 1 < nst) {
        const int s0n = (st + 1) * 64;
        const int swz = ((lane & 7) ^ (lane >> 3)) << 3;
        #pragma unroll
        for (int p = 0; p < 2; ++p) {
            const int chunk = w * 2 + p;
            __builtin_amdgcn_global_load_lds(
                (GV*)(kbase + (size_t)(s0n + chunk * 8 + (lane >> 3)) * 64 + swz),
                (LV*)(&sh->Ks[cur ^ 1][chunk * 512]), 16, 0, 0);
        }
        const unsigned short* vp = vbase + (size_t)(s0n + lane) * 64 + w * 16;
        vn_n[0] = *(const ushort8*)&vp[0];
        vn_n[1] = *(const ushort8*)&vp[8];
    }
    // 3. K fragments (swizzled read), shared by both q-tiles
    bf16x8 kb0[4], kb1[4];
    #pragma unroll
    for (int nt = 0; nt < 4; ++nt) {
        const int row = nt * 16 + lx;
        kb0[nt] = *(const bf16x8*)&sh->Ks[cur][row * 64 + ((hi ^ r7) << 3)];
        kb1[nt] = *(const bf16x8*)&sh->Ks[cur][row * 64 + (((4 + hi) ^ r7) << 3)];
    }
    const int trel = 16 * w + hi * 4;
    // 4. compute: B every tile; A while st <= lastA
    attn_compute(st == nst - 1, trel, w, lx, hi, r7, cur, sh, kb0, kb1, aqB, oB, lB);
    if (st <= lastA)
        attn_compute(st == lastA, trel, w, lx, hi, r7, cur, sh, kb0, kb1, aqA, oA, lA);
}

__global__ __launch_bounds__(256) void attn_kernel(
    const unsigned short* __restrict__ qh, const unsigned short* __restrict__ kf,
    const unsigned short* __restrict__ vf, unsigned short* __restrict__ y)
{
    __shared__ AttnShared sh;
    const int p = blockIdx.x;                  // pair index 0..15
    const int h = blockIdx.y, b = blockIdx.z;
    const int kv = h >> 2;
    const int jA = p, jB = 31 - p;
    const int t0A = jA * 64, t0B = jB * 64;
    const int tid = threadIdx.x, w = tid >> 6, lane = tid & 63;
    const int lx = lane & 15, hi = lane >> 4;

    bf16x8 aqA[2], aqB[2];
    {
        const unsigned short* qp = qh + ((size_t)(b * NH + h) * T + t0A + 16 * w + lx) * 64;
        aqA[0] = *(const bf16x8*)&qp[hi * 8];
        aqA[1] = *(const bf16x8*)&qp[32 + hi * 8];
        const unsigned short* qb = qh + ((size_t)(b * NH + h) * T + t0B + 16 * w + lx) * 64;
        aqB[0] = *(const bf16x8*)&qb[hi * 8];
        aqB[1] = *(const bf16x8*)&qb[32 + hi * 8];
    }
    f32x4 oA[4], oB[4];
    float lA[4], lB[4];
    #pragma unroll
    for (int dt = 0; dt < 4; ++dt) {
        oA[dt] = (f32x4){0.f, 0.f, 0.f, 0.f};
        oB[dt] = (f32x4){0.f, 0.f, 0.f, 0.f};
    }
    #pragma unroll
    for (int r = 0; r < 4; ++r) { lA[r] = 0.f; lB[r] = 0.f; }

    const unsigned short* kbase = kf + (size_t)(b * NKV + kv) * S_TOT * 64;
    const unsigned short* vbase = vf + (size_t)(b * NKV + kv) * S_TOT * 64;

    const int nst = jB + 2;          // 18..33
    const int lastA = jA + 1;
    // prologue: stage K tile 0 -> Ks[0]; V tile 0 -> regs
    {
        const int swz = ((lane & 7) ^ (lane >> 3)) << 3;
        #pragma unroll
        for (int q = 0; q < 2; ++q) {
            const int chunk = w * 2 + q;
            __builtin_amdgcn_global_load_lds(
                (GV*)(kbase + (size_t)(chunk * 8 + (lane >> 3)) * 64 + swz),
                (LV*)(&sh.Ks[0][chunk * 512]), 16, 0, 0);
        }
    }
    ushort8 vnA[2], vnB[2];
    {
        const unsigned short* vp = vbase + (size_t)lane * 64 + w * 16;
        vnA[0] = *(const ushort8*)&vp[0];
        vnA[1] = *(const ushort8*)&vp[8];
    }
    for (int st = 0; st < nst; st += 2) {
        attn_tile(st, nst, lastA, w, lane, lx, hi, kbase, vbase, &sh,
                  vnA, vnB, aqA, aqB, oA, lA, oB, lB);
        if (st + 1 < nst)
            attn_tile(st + 1, nst, lastA, w, lane, lx, hi, kbase, vbase, &sh,
                      vnB, vnA, aqA, aqB, oA, lA, oB, lB);
    }

    // epilogue: l-reduce + write both q-tiles
    #pragma unroll
    for (int qi = 0; qi < 2; ++qi) {
        const int t0 = qi ? t0B : t0A;
        f32x4* o = qi ? oB : oA;
        float* l_r = qi ? lB : lA;
        float lt[4];
        #pragma unroll
        for (int r = 0; r < 4; ++r) {
            float v = l_r[r];
            #pragma unroll
            for (int off = 1; off < 16; off <<= 1) v += __shfl_xor(v, off, 64);
            lt[r] = 1.f / v;
        }
        #pragma unroll
        for (int dt = 0; dt < 4; ++dt)
            #pragma unroll
            for (int r = 0; r < 4; ++r) {
                int t = t0 + 16 * w + hi * 4 + r;
                y[((size_t)(b * T) + t) * 1024 + h * 64 + dt * 16 + lx] =
                    f2bf(o[dt][r] * lt[r]);
            }
    }
}

// ----------------------------------------------------------------- launcher
extern "C" void kernel_launch(void* const* d_in, const int* in_sizes, int n_in,
                              void* d_out, int out_size, void* d_ws, size_t ws_size,
                              hipStream_t stream)
{
    const float* x     = (const float*)d_in[0];
    const float* ve    = (const float*)d_in[1];
    const float* cosb  = (const float*)d_in[2];
    const float* sinb  = (const float*)d_in[3];
    const float* Wq    = (const float*)d_in[4];
    const float* Wk    = (const float*)d_in[5];
    const float* Wv    = (const float*)d_in[6];
    const float* Wproj = (const float*)d_in[7];
    const float* Wg    = (const float*)d_in[8];
    const float* memk  = (const float*)d_in[9];
    const float* memv  = (const float*)d_in[10];
    const float* vscal = (const float*)d_in[11];

    unsigned short* xh    = (unsigned short*)d_ws;
    unsigned short* wqkv  = xh + (size_t)4096 * 1024;
    unsigned short* wproj = wqkv + (size_t)1536 * 1024;
    unsigned short* qhb   = wproj + (size_t)1024 * 1024;
    unsigned short* kfull = qhb + (size_t)4096 * 1024;
    unsigned short* vfull = kfull + (size_t)B * NKV * S_TOT * 64;
    unsigned short* qkvb  = vfull + (size_t)B * NKV * S_TOT * 64;
    unsigned short* ybuf  = xh;   // alias: xh dead after QKV GEMM
    float* out = (float*)d_out;

    const dim3 blk(256);
    // one fused cast: x | Wq | Wk | Wv | Wproj -> contiguous bf16 region at ws
    cast_all<<<dim3(6656), blk, 0, stream>>>(x, Wq, Wk, Wv, Wproj, xh);

    gemm_bf16<true><<<dim3(12, 32), blk, 0, stream>>>(xh, wqkv, qkvb, 1536, 1024);
    fuse_kernel<<<dim3(B * T), blk, 0, stream>>>(x, ve, cosb, sinb, Wg, qkvb,
                                                 qhb, kfull, vfull);
    mem_kernel<<<dim3(B * M), blk, 0, stream>>>(memk, memv, vscal, kfull, vfull);
    attn_kernel<<<dim3(16, NH, B), blk, 0, stream>>>(qhb, kfull, vfull, ybuf);
    gemm_bf16<false><<<dim3(8, 32), blk, 0, stream>>>(ybuf, wproj, out, 1024, 1024);
}

// Round 11
// 113.581 us; speedup vs baseline: 1.7663x; 1.0116x over previous
//
#include <hip/hip_runtime.h>
#include <hip/hip_bf16.h>
#include <math.h>

#define B 2
#define T 2048
#define C 1024
#define NH 16
#define NKV 4
#define HD 64
#define M 64
#define GC 32
#define S_TOT (M + T)   // 2112
#define EPS 1e-6f
// |score| bound in exp2 domain: ||q||*||k|| = (8*0.2164)*(8*1.2) = 16.62
#define FIXED_MAX 17.0f

using bf16x8  = __attribute__((ext_vector_type(8))) __bf16;
using f32x4   = __attribute__((ext_vector_type(4))) float;
using ushort8 = __attribute__((ext_vector_type(8))) unsigned short;
using ushort4v= __attribute__((ext_vector_type(4))) unsigned short;

typedef __attribute__((address_space(1))) const void GV;
typedef __attribute__((address_space(3))) void LV;

__device__ inline unsigned short f2bf(float f) {
    __bf16 h = (__bf16)f;
    return __builtin_bit_cast(unsigned short, h);
}
__device__ inline float bf2f(unsigned short u) {
    unsigned int x = (unsigned int)u << 16;
    return __builtin_bit_cast(float, x);
}
__device__ inline float wave_sum(float v) {
    #pragma unroll
    for (int off = 32; off; off >>= 1) v += __shfl_xor(v, off, 64);
    return v;
}
__device__ __forceinline__ float exp2_raw(float x) {
    float y;
    asm("v_exp_f32 %0, %1" : "=v"(y) : "v"(x));
    return y;
}
__device__ __forceinline__ unsigned int cvt_pk_bf16(float lo, float hi) {
    unsigned int u;
    asm("v_cvt_pk_bf16_f32 %0, %1, %2" : "=v"(u) : "v"(lo), "v"(hi));
    return u;
}

// ----------------------------------------- fused fp32 -> bf16 (all 5 inputs)
__global__ __launch_bounds__(256) void cast_all(
    const float* __restrict__ s0, const float* __restrict__ s1,
    const float* __restrict__ s2, const float* __restrict__ s3,
    const float* __restrict__ s4, unsigned short* __restrict__ dst)
{
    const int i = blockIdx.x * 256 + threadIdx.x;   // float4 index, 1703936 total
    const float* src; int off;
    if      (i < 1048576) { src = s0; off = i; }
    else if (i < 1310720) { src = s1; off = i - 1048576; }
    else if (i < 1376256) { src = s2; off = i - 1310720; }
    else if (i < 1441792) { src = s3; off = i - 1376256; }
    else                  { src = s4; off = i - 1441792; }
    float4 v = ((const float4*)src)[off];
    ushort4v o;
    o.x = f2bf(v.x); o.y = f2bf(v.y); o.z = f2bf(v.z); o.w = f2bf(v.w);
    ((ushort4v*)dst)[i] = o;
}

// ------------------------------------------------------- bf16 MFMA GEMM (m97)
template<bool OUT_BF16>
__global__ __launch_bounds__(256) void gemm_bf16(
    const unsigned short* __restrict__ A, const unsigned short* __restrict__ Bt,
    void* __restrict__ Cc, int Nn, int Kk)
{
    __shared__ unsigned short As[128 * 64];
    __shared__ unsigned short Bs[128 * 64];
    const int tid = threadIdx.x;
    const int w = tid >> 6, lane = tid & 63, lx = lane & 15, hi = lane >> 4;
    const int wr = w >> 1, wc = w & 1;
    const int m0 = blockIdx.y * 128, n0 = blockIdx.x * 128;
    const int lrow = lane >> 3;
    const int lcol = (lane & 7) * 8;

    f32x4 acc[4][4];
    #pragma unroll
    for (int mi = 0; mi < 4; ++mi)
        #pragma unroll
        for (int ni = 0; ni < 4; ++ni) acc[mi][ni] = (f32x4){0.f, 0.f, 0.f, 0.f};

    for (int k0 = 0; k0 < Kk; k0 += 64) {
        #pragma unroll
        for (int p = 0; p < 4; ++p) {
            const int chunk = w * 4 + p;
            const int row = chunk * 8 + lrow;
            __builtin_amdgcn_global_load_lds(
                (GV*)(A + (size_t)(m0 + row) * Kk + k0 + lcol),
                (LV*)(As + chunk * 512), 16, 0, 0);
            __builtin_amdgcn_global_load_lds(
                (GV*)(Bt + (size_t)(n0 + row) * Kk + k0 + lcol),
                (LV*)(Bs + chunk * 512), 16, 0, 0);
        }
        __syncthreads();
        #pragma unroll
        for (int kk = 0; kk < 2; ++kk) {
            bf16x8 af[4], bfr[4];
            #pragma unroll
            for (int mi = 0; mi < 4; ++mi)
                af[mi] = *(const bf16x8*)&As[(wr * 64 + mi * 16 + lx) * 64 + kk * 32 + hi * 8];
            #pragma unroll
            for (int ni = 0; ni < 4; ++ni)
                bfr[ni] = *(const bf16x8*)&Bs[(wc * 64 + ni * 16 + lx) * 64 + kk * 32 + hi * 8];
            #pragma unroll
            for (int mi = 0; mi < 4; ++mi)
                #pragma unroll
                for (int ni = 0; ni < 4; ++ni)
                    acc[mi][ni] = __builtin_amdgcn_mfma_f32_16x16x32_bf16(
                        af[mi], bfr[ni], acc[mi][ni], 0, 0, 0);
        }
        __syncthreads();
    }
    #pragma unroll
    for (int mi = 0; mi < 4; ++mi)
        #pragma unroll
        for (int ni = 0; ni < 4; ++ni)
            #pragma unroll
            for (int r = 0; r < 4; ++r) {
                size_t idx = (size_t)(m0 + wr * 64 + mi * 16 + hi * 4 + r) * Nn
                           + n0 + wc * 64 + ni * 16 + lx;
                if constexpr (OUT_BF16) ((unsigned short*)Cc)[idx] = f2bf(acc[mi][ni][r]);
                else                    ((float*)Cc)[idx] = acc[mi][ni][r];
            }
}

// ------------------------------------------------- gate + RoPE + RMS fusion
// q scale folds 1/sqrt(HD) AND log2(e): 1.2 * 0.125 * 1.44269504 = 0.21640426
__global__ __launch_bounds__(256) void fuse_kernel(
    const float* __restrict__ x, const float* __restrict__ ve,
    const float* __restrict__ cosb, const float* __restrict__ sinb,
    const float* __restrict__ Wg, const unsigned short* __restrict__ qkv,
    unsigned short* __restrict__ qh, unsigned short* __restrict__ kfull,
    unsigned short* __restrict__ vfull)
{
    const int bt = blockIdx.x;
    const int b = bt >> 11, t = bt & (T - 1);
    const int w = threadIdx.x >> 6, l = threadIdx.x & 63, i = l & 31;
    const float c = cosb[t * 32 + i];
    const float s = sinb[t * 32 + i];
    const unsigned short* row = qkv + (size_t)bt * 1536;

    #pragma unroll
    for (int hq = 0; hq < 4; ++hq) {
        const int h = w + hq * 4;
        float x1 = bf2f(row[h * 64 + i]);
        float x2 = bf2f(row[h * 64 + i + 32]);
        float val = (l < 32) ? (x1 * c - x2 * s) : (x1 * s + x2 * c);
        float ss = wave_sum(val * val);
        float scale = rsqrtf(ss * (1.f / 64.f) + EPS) * 0.21640426f;
        qh[((size_t)(b * NH + h) * T + t) * 64 + l] = f2bf(val * scale);
    }
    {
        float x1 = bf2f(row[1024 + w * 64 + i]);
        float x2 = bf2f(row[1024 + w * 64 + i + 32]);
        float val = (l < 32) ? (x1 * c - x2 * s) : (x1 * s + x2 * c);
        float ss = wave_sum(val * val);
        float scale = rsqrtf(ss * (1.f / 64.f) + EPS) * 1.2f;
        kfull[((size_t)(b * NKV + w) * S_TOT + M + t) * 64 + l] = f2bf(val * scale);
    }
    {
        const float* xr = x + (size_t)bt * 1024;
        float g = 0.f;
        #pragma unroll
        for (int gi = 0; gi < GC; ++gi) g += xr[gi] * Wg[w * GC + gi];
        g = 3.f / (1.f + __expf(-g));
        float vv = bf2f(row[1280 + w * 64 + l]) + g * ve[(size_t)bt * 256 + w * 64 + l];
        vfull[((size_t)(b * NKV + w) * S_TOT + M + t) * 64 + l] = f2bf(vv);
    }
}

// ------------------------------------------------------- memory token prep
__global__ __launch_bounds__(256) void mem_kernel(
    const float* __restrict__ mem_k, const float* __restrict__ mem_v,
    const float* __restrict__ vscal,
    unsigned short* __restrict__ kfull, unsigned short* __restrict__ vfull)
{
    const int bm = blockIdx.x;
    const int b = bm >> 6, mr = bm & 63;
    const int w = threadIdx.x >> 6, l = threadIdx.x & 63;
    const size_t src = ((size_t)mr * NKV + w) * HD + l;
    float kvv = mem_k[src];
    float ss = wave_sum(kvv * kvv);
    float scale = rsqrtf(ss * (1.f / 64.f) + EPS) * 1.2f;
    const size_t dst = ((size_t)(b * NKV + w) * S_TOT + mr) * 64 + l;
    kfull[dst] = f2bf(kvv * scale);
    vfull[dst] = f2bf(mem_v[src] * vscal[0]);
}

// -------------------------------------------------------- MFMA flash attn v11
// 8 waves x 512 threads: waves 0-3 own q-tile A (jA=p), waves 4-7 own B
// (jB=31-p). Same 512-block grid, double the waves/SIMD for latency hiding.
// Each wave: ONE attn_compute per s-tile; A-waves skip compute past their
// diagonal (block-uniform). Fixed-max softmax + sigma-pack P store (R10).
struct AttnShared {
    unsigned short Ks[2][4096];   // [buf][row*64 + swz-col]      (K[s][d])
    unsigned short Vt[2][4096];   // [buf][row*64 + swz(sigma(s))] (V^T[d][q])
    unsigned short Ps[128 * 64];  // [row*64 + swz(q)]            (P[t][q])
};

__device__ __forceinline__ void attn_compute(
    const bool diag, const int trel, const int pbase,
    const int lx, const int hi, const int r7, const int cur,
    AttnShared* sh, const bf16x8 (&kb0)[4], const bf16x8 (&kb1)[4],
    const bf16x8 (&aq)[2],
    f32x4 (&o_acc)[4], float (&l_r)[4])
{
    // S = Q K^T - FIXED_MAX (shift folded into C-init)
    f32x4 s_acc[4];
    #pragma unroll
    for (int nt = 0; nt < 4; ++nt) {
        s_acc[nt] = (f32x4){-FIXED_MAX, -FIXED_MAX, -FIXED_MAX, -FIXED_MAX};
        s_acc[nt] = __builtin_amdgcn_mfma_f32_16x16x32_bf16(aq[0], kb0[nt], s_acc[nt], 0, 0, 0);
        s_acc[nt] = __builtin_amdgcn_mfma_f32_16x16x32_bf16(aq[1], kb1[nt], s_acc[nt], 0, 0, 0);
    }
    if (diag) {
        #pragma unroll
        for (int r = 0; r < 4; ++r) {
            const int thr = trel + r;
            #pragma unroll
            for (int nt = 0; nt < 4; ++nt)
                if (nt * 16 + lx > thr) s_acc[nt][r] = -INFINITY;
        }
    }
    // exp2 (bare v_exp_f32) + packed bf16 store: q-positions lx*4+nt
    #pragma unroll
    for (int r = 0; r < 4; ++r) {
        const int prow = pbase + hi * 4 + r;
        const float p0 = exp2_raw(s_acc[0][r]);
        const float p1 = exp2_raw(s_acc[1][r]);
        const float p2 = exp2_raw(s_acc[2][r]);
        const float p3 = exp2_raw(s_acc[3][r]);
        l_r[r] += (p0 + p1) + (p2 + p3);
        uint2 pk;
        pk.x = cvt_pk_bf16(p0, p1);
        pk.y = cvt_pk_bf16(p2, p3);
        const int idx = prow * 64 + ((((lx >> 1) ^ (prow & 7)) << 3) | ((lx & 1) << 2));
        *(uint2*)&sh->Ps[idx] = pk;   // 8B-aligned
    }
    // O += P V   (read addressing: group-XOR with r7)
    #pragma unroll
    for (int kk = 0; kk < 2; ++kk) {
        bf16x8 pa = *(const bf16x8*)&sh->Ps[(pbase + lx) * 64 + (((kk * 4 + hi) ^ r7) << 3)];
        #pragma unroll
        for (int dt = 0; dt < 4; ++dt) {
            bf16x8 vb = *(const bf16x8*)&sh->Vt[cur][(dt * 16 + lx) * 64 + (((kk * 4 + hi) ^ r7) << 3)];
            o_acc[dt] = __builtin_amdgcn_mfma_f32_16x16x32_bf16(pa, vb, o_acc[dt], 0, 0, 0);
        }
    }
}

__device__ __forceinline__ void attn_tile(
    const int st, const int nst, const int dtile, const int trel, const int pbase,
    const int w, const int lane, const int lx, const int hi,
    const unsigned short* __restrict__ kbase,
    const unsigned short* __restrict__ vbase,
    AttnShared* sh, ushort8& vn_c, ushort8& vn_n,
    const bf16x8 (&aq)[2],
    f32x4 (&o_acc)[4], float (&l_r)[4])
{
    const int cur = st & 1;
    const int r7 = lx & 7;
    // 1. write prefetched V (tile st) into Vt[cur] at sigma-permuted column
    const int q = (lane & 15) * 4 + (lane >> 4);   // sigma(s), s = lane
    #pragma unroll
    for (int j = 0; j < 8; ++j) {
        const int row = w * 8 + j;                 // d index (8 waves x 8 rows)
        sh->Vt[cur][row * 64 + ((((q >> 3) ^ (row & 7)) << 3) | (q & 7))] =
            (unsigned short)vn_c[j];
    }
    __syncthreads();   // drains K gload_lds for tile st; publishes Vt[cur]
    // 2. prefetch tile st+1 (8 waves x 8 rows = full 64-row K tile)
    if (st + 1 < nst) {
        const int s0n = (st + 1) * 64;
        const int swz = ((lane & 7) ^ (lane >> 3)) << 3;
        __builtin_amdgcn_global_load_lds(
            (GV*)(kbase + (size_t)(s0n + w * 8 + (lane >> 3)) * 64 + swz),
            (LV*)(&sh->Ks[cur ^ 1][w * 512]), 16, 0, 0);
        vn_n = *(const ushort8*)&vbase[(size_t)(s0n + lane) * 64 + w * 8];
    }
    if (st > dtile) return;   // fully masked for this wave: staging+barrier only
    // 3. K fragments (swizzled read)
    bf16x8 kb0[4], kb1[4];
    #pragma unroll
    for (int nt = 0; nt < 4; ++nt) {
        const int row = nt * 16 + lx;
        kb0[nt] = *(const bf16x8*)&sh->Ks[cur][row * 64 + ((hi ^ r7) << 3)];
        kb1[nt] = *(const bf16x8*)&sh->Ks[cur][row * 64 + (((4 + hi) ^ r7) << 3)];
    }
    // 4. compute this wave's q-tile
    attn_compute(st == dtile, trel, pbase, lx, hi, r7, cur, sh, kb0, kb1, aq, o_acc, l_r);
}

__global__ __launch_bounds__(512) void attn_kernel(
    const unsigned short* __restrict__ qh, const unsigned short* __restrict__ kf,
    const unsigned short* __restrict__ vf, unsigned short* __restrict__ y)
{
    __shared__ AttnShared sh;
    const int p = blockIdx.x;                  // pair index 0..15
    const int h = blockIdx.y, b = blockIdx.z;
    const int kv = h >> 2;
    const int jA = p, jB = 31 - p;
    const int tid = threadIdx.x, w = tid >> 6, lane = tid & 63;
    const int lx = lane & 15, hi = lane >> 4;
    const int qsel = w >> 2, wl = w & 3;       // waves 0-3: A, waves 4-7: B
    const int t0q = (qsel ? jB : jA) * 64;
    const int dtile = (qsel ? jB : jA) + 1;    // this wave's diagonal s-tile
    const int trel = 16 * wl + hi * 4;
    const int pbase = w * 16;

    bf16x8 aq[2];
    {
        const unsigned short* qp = qh + ((size_t)(b * NH + h) * T + t0q + 16 * wl + lx) * 64;
        aq[0] = *(const bf16x8*)&qp[hi * 8];
        aq[1] = *(const bf16x8*)&qp[32 + hi * 8];
    }
    f32x4 o_acc[4];
    float l_r[4];
    #pragma unroll
    for (int dt = 0; dt < 4; ++dt) o_acc[dt] = (f32x4){0.f, 0.f, 0.f, 0.f};
    #pragma unroll
    for (int r = 0; r < 4; ++r) l_r[r] = 0.f;

    const unsigned short* kbase = kf + (size_t)(b * NKV + kv) * S_TOT * 64;
    const unsigned short* vbase = vf + (size_t)(b * NKV + kv) * S_TOT * 64;

    const int nst = jB + 2;          // 18..33
    // prologue: stage K tile 0 -> Ks[0] (one call per wave); V tile 0 -> regs
    {
        const int swz = ((lane & 7) ^ (lane >> 3)) << 3;
        __builtin_amdgcn_global_load_lds(
            (GV*)(kbase + (size_t)(w * 8 + (lane >> 3)) * 64 + swz),
            (LV*)(&sh.Ks[0][w * 512]), 16, 0, 0);
    }
    ushort8 vnA, vnB;
    vnA = *(const ushort8*)&vbase[(size_t)lane * 64 + w * 8];
    for (int st = 0; st < nst; st += 2) {
        attn_tile(st, nst, dtile, trel, pbase, w, lane, lx, hi, kbase, vbase, &sh,
                  vnA, vnB, aq, o_acc, l_r);
        if (st + 1 < nst)
            attn_tile(st + 1, nst, dtile, trel, pbase, w, lane, lx, hi, kbase, vbase, &sh,
                      vnB, vnA, aq, o_acc, l_r);
    }

    // epilogue: l-reduce + write this wave's 16 rows
    float lt[4];
    #pragma unroll
    for (int r = 0; r < 4; ++r) {
        float v = l_r[r];
        #pragma unroll
        for (int off = 1; off < 16; off <<= 1) v += __shfl_xor(v, off, 64);
        lt[r] = 1.f / v;
    }
    #pragma unroll
    for (int dt = 0; dt < 4; ++dt)
        #pragma unroll
        for (int r = 0; r < 4; ++r) {
            int t = t0q + 16 * wl + hi * 4 + r;
            y[((size_t)(b * T) + t) * 1024 + h * 64 + dt * 16 + lx] =
                f2bf(o_acc[dt][r] * lt[r]);
        }
}

// ----------------------------------------------------------------- launcher
extern "C" void kernel_launch(void* const* d_in, const int* in_sizes, int n_in,
                              void* d_out, int out_size, void* d_ws, size_t ws_size,
                              hipStream_t stream)
{
    const float* x     = (const float*)d_in[0];
    const float* ve    = (const float*)d_in[1];
    const float* cosb  = (const float*)d_in[2];
    const float* sinb  = (const float*)d_in[3];
    const float* Wq    = (const float*)d_in[4];
    const float* Wk    = (const float*)d_in[5];
    const float* Wv    = (const float*)d_in[6];
    const float* Wproj = (const float*)d_in[7];
    const float* Wg    = (const float*)d_in[8];
    const float* memk  = (const float*)d_in[9];
    const float* memv  = (const float*)d_in[10];
    const float* vscal = (const float*)d_in[11];

    unsigned short* xh    = (unsigned short*)d_ws;
    unsigned short* wqkv  = xh + (size_t)4096 * 1024;
    unsigned short* wproj = wqkv + (size_t)1536 * 1024;
    unsigned short* qhb   = wproj + (size_t)1024 * 1024;
    unsigned short* kfull = qhb + (size_t)4096 * 1024;
    unsigned short* vfull = kfull + (size_t)B * NKV * S_TOT * 64;
    unsigned short* qkvb  = vfull + (size_t)B * NKV * S_TOT * 64;
    unsigned short* ybuf  = xh;   // alias: xh dead after QKV GEMM
    float* out = (float*)d_out;

    const dim3 blk(256);
    // one fused cast: x | Wq | Wk | Wv | Wproj -> contiguous bf16 region at ws
    cast_all<<<dim3(6656), blk, 0, stream>>>(x, Wq, Wk, Wv, Wproj, xh);

    gemm_bf16<true><<<dim3(12, 32), blk, 0, stream>>>(xh, wqkv, qkvb, 1536, 1024);
    fuse_kernel<<<dim3(B * T), blk, 0, stream>>>(x, ve, cosb, sinb, Wg, qkvb,
                                                 qhb, kfull, vfull);
    mem_kernel<<<dim3(B * M), blk, 0, stream>>>(memk, memv, vscal, kfull, vfull);
    attn_kernel<<<dim3(16, NH, B), dim3(512), 0, stream>>>(qhb, kfull, vfull, ybuf);
    gemm_bf16<false><<<dim3(8, 32), blk, 0, stream>>>(ybuf, wproj, out, 1024, 1024);
}

// Round 14
// 110.971 us; speedup vs baseline: 1.8079x; 1.0235x over previous
//
#include <hip/hip_runtime.h>
#include <hip/hip_bf16.h>
#include <math.h>

#define B 2
#define T 2048
#define C 1024
#define NH 16
#define NKV 4
#define HD 64
#define M 64
#define GC 32
#define S_TOT (M + T)   // 2112
#define EPS 1e-6f
// |score| bound in exp2 domain: ||q||*||k|| = (8*0.2164)*(8*1.2) = 16.62
#define FIXED_MAX 17.0f

using bf16x8  = __attribute__((ext_vector_type(8))) __bf16;
using f32x4   = __attribute__((ext_vector_type(4))) float;
using ushort8 = __attribute__((ext_vector_type(8))) unsigned short;
using ushort4v= __attribute__((ext_vector_type(4))) unsigned short;

typedef __attribute__((address_space(1))) const void GV;
typedef __attribute__((address_space(3))) void LV;

__device__ inline unsigned short f2bf(float f) {
    __bf16 h = (__bf16)f;
    return __builtin_bit_cast(unsigned short, h);
}
__device__ inline float bf2f(unsigned short u) {
    unsigned int x = (unsigned int)u << 16;
    return __builtin_bit_cast(float, x);
}
__device__ inline float wave_sum(float v) {
    #pragma unroll
    for (int off = 32; off; off >>= 1) v += __shfl_xor(v, off, 64);
    return v;
}
__device__ __forceinline__ float exp2_raw(float x) {
    float y;
    asm("v_exp_f32 %0, %1" : "=v"(y) : "v"(x));
    return y;
}
__device__ __forceinline__ unsigned int cvt_pk_bf16(float lo, float hi) {
    unsigned int u;
    asm("v_cvt_pk_bf16_f32 %0, %1, %2" : "=v"(u) : "v"(lo), "v"(hi));
    return u;
}

// ----------------------------------------- fused fp32 -> bf16 (all 5 inputs)
__global__ __launch_bounds__(256) void cast_all(
    const float* __restrict__ s0, const float* __restrict__ s1,
    const float* __restrict__ s2, const float* __restrict__ s3,
    const float* __restrict__ s4, unsigned short* __restrict__ dst)
{
    const int i = blockIdx.x * 256 + threadIdx.x;   // float4 index, 1703936 total
    const float* src; int off;
    if      (i < 1048576) { src = s0; off = i; }
    else if (i < 1310720) { src = s1; off = i - 1048576; }
    else if (i < 1376256) { src = s2; off = i - 1310720; }
    else if (i < 1441792) { src = s3; off = i - 1376256; }
    else                  { src = s4; off = i - 1441792; }
    float4 v = ((const float4*)src)[off];
    ushort4v o;
    o.x = f2bf(v.x); o.y = f2bf(v.y); o.z = f2bf(v.z); o.w = f2bf(v.w);
    ((ushort4v*)dst)[i] = o;
}

// --------------------------- QKV GEMM, BM=64 core, RAW bf16 output (bisect)
// BM=64, BN=128, BK=64, 4 waves 2x2 (wave-tile 32x64). Epilogue = plain
// bf16 store to qkvb [row][1536] (the proven gemm_bf16<true> pattern).
__global__ __launch_bounds__(256) void qkv_gemm_raw(
    const unsigned short* __restrict__ A, const unsigned short* __restrict__ Bt,
    unsigned short* __restrict__ Cc)
{
    __shared__ unsigned short As[64 * 64];
    __shared__ unsigned short Bs[128 * 64];
    const int tid = threadIdx.x;
    const int w = tid >> 6, lane = tid & 63, lx = lane & 15, hi = lane >> 4;
    const int wr = w >> 1, wc = w & 1;
    const int m0 = blockIdx.y * 64, n0 = blockIdx.x * 128;
    const int lrow = lane >> 3;
    const int lcol = (lane & 7) * 8;

    f32x4 acc[2][4];
    #pragma unroll
    for (int mi = 0; mi < 2; ++mi)
        #pragma unroll
        for (int ni = 0; ni < 4; ++ni) acc[mi][ni] = (f32x4){0.f, 0.f, 0.f, 0.f};

    for (int k0 = 0; k0 < 1024; k0 += 64) {
        #pragma unroll
        for (int p = 0; p < 2; ++p) {           // A: 8 chunks, 2/wave
            const int chunk = w * 2 + p;
            __builtin_amdgcn_global_load_lds(
                (GV*)(A + (size_t)(m0 + chunk * 8 + lrow) * 1024 + k0 + lcol),
                (LV*)(As + chunk * 512), 16, 0, 0);
        }
        #pragma unroll
        for (int p = 0; p < 4; ++p) {           // B: 16 chunks, 4/wave
            const int chunk = w * 4 + p;
            __builtin_amdgcn_global_load_lds(
                (GV*)(Bt + (size_t)(n0 + chunk * 8 + lrow) * 1024 + k0 + lcol),
                (LV*)(Bs + chunk * 512), 16, 0, 0);
        }
        __syncthreads();
        #pragma unroll
        for (int kk = 0; kk < 2; ++kk) {
            bf16x8 af[2], bfr[4];
            #pragma unroll
            for (int mi = 0; mi < 2; ++mi)
                af[mi] = *(const bf16x8*)&As[(wr * 32 + mi * 16 + lx) * 64 + kk * 32 + hi * 8];
            #pragma unroll
            for (int ni = 0; ni < 4; ++ni)
                bfr[ni] = *(const bf16x8*)&Bs[(wc * 64 + ni * 16 + lx) * 64 + kk * 32 + hi * 8];
            #pragma unroll
            for (int mi = 0; mi < 2; ++mi)
                #pragma unroll
                for (int ni = 0; ni < 4; ++ni)
                    acc[mi][ni] = __builtin_amdgcn_mfma_f32_16x16x32_bf16(
                        af[mi], bfr[ni], acc[mi][ni], 0, 0, 0);
        }
        __syncthreads();
    }
    #pragma unroll
    for (int mi = 0; mi < 2; ++mi)
        #pragma unroll
        for (int ni = 0; ni < 4; ++ni)
            #pragma unroll
            for (int r = 0; r < 4; ++r)
                Cc[(size_t)(m0 + wr * 32 + mi * 16 + hi * 4 + r) * 1536
                   + n0 + wc * 64 + ni * 16 + lx] = f2bf(acc[mi][ni][r]);
}

// ------------------------------------------------- gate + RoPE + RMS fusion
// (R11 verbatim) q scale folds 1/sqrt(HD) AND log2(e)
__global__ __launch_bounds__(256) void fuse_kernel(
    const float* __restrict__ x, const float* __restrict__ ve,
    const float* __restrict__ cosb, const float* __restrict__ sinb,
    const float* __restrict__ Wg, const unsigned short* __restrict__ qkv,
    unsigned short* __restrict__ qh, unsigned short* __restrict__ kfull,
    unsigned short* __restrict__ vfull)
{
    const int bt = blockIdx.x;
    const int b = bt >> 11, t = bt & (T - 1);
    const int w = threadIdx.x >> 6, l = threadIdx.x & 63, i = l & 31;
    const float c = cosb[t * 32 + i];
    const float s = sinb[t * 32 + i];
    const unsigned short* row = qkv + (size_t)bt * 1536;

    #pragma unroll
    for (int hq = 0; hq < 4; ++hq) {
        const int h = w + hq * 4;
        float x1 = bf2f(row[h * 64 + i]);
        float x2 = bf2f(row[h * 64 + i + 32]);
        float val = (l < 32) ? (x1 * c - x2 * s) : (x1 * s + x2 * c);
        float ss = wave_sum(val * val);
        float scale = rsqrtf(ss * (1.f / 64.f) + EPS) * 0.21640426f;
        qh[((size_t)(b * NH + h) * T + t) * 64 + l] = f2bf(val * scale);
    }
    {
        float x1 = bf2f(row[1024 + w * 64 + i]);
        float x2 = bf2f(row[1024 + w * 64 + i + 32]);
        float val = (l < 32) ? (x1 * c - x2 * s) : (x1 * s + x2 * c);
        float ss = wave_sum(val * val);
        float scale = rsqrtf(ss * (1.f / 64.f) + EPS) * 1.2f;
        kfull[((size_t)(b * NKV + w) * S_TOT + M + t) * 64 + l] = f2bf(val * scale);
    }
    {
        const float* xr = x + (size_t)bt * 1024;
        float g = 0.f;
        #pragma unroll
        for (int gi = 0; gi < GC; ++gi) g += xr[gi] * Wg[w * GC + gi];
        g = 3.f / (1.f + __expf(-g));
        float vv = bf2f(row[1280 + w * 64 + l]) + g * ve[(size_t)bt * 256 + w * 64 + l];
        vfull[((size_t)(b * NKV + w) * S_TOT + M + t) * 64 + l] = f2bf(vv);
    }
}

// ------------------------------------------------------- bf16 MFMA GEMM (m97)
template<bool OUT_BF16>
__global__ __launch_bounds__(256) void gemm_bf16(
    const unsigned short* __restrict__ A, const unsigned short* __restrict__ Bt,
    void* __restrict__ Cc, int Nn, int Kk)
{
    __shared__ unsigned short As[128 * 64];
    __shared__ unsigned short Bs[128 * 64];
    const int tid = threadIdx.x;
    const int w = tid >> 6, lane = tid & 63, lx = lane & 15, hi = lane >> 4;
    const int wr = w >> 1, wc = w & 1;
    const int m0 = blockIdx.y * 128, n0 = blockIdx.x * 128;
    const int lrow = lane >> 3;
    const int lcol = (lane & 7) * 8;

    f32x4 acc[4][4];
    #pragma unroll
    for (int mi = 0; mi < 4; ++mi)
        #pragma unroll
        for (int ni = 0; ni < 4; ++ni) acc[mi][ni] = (f32x4){0.f, 0.f, 0.f, 0.f};

    for (int k0 = 0; k0 < Kk; k0 += 64) {
        #pragma unroll
        for (int p = 0; p < 4; ++p) {
            const int chunk = w * 4 + p;
            const int row = chunk * 8 + lrow;
            __builtin_amdgcn_global_load_lds(
                (GV*)(A + (size_t)(m0 + row) * Kk + k0 + lcol),
                (LV*)(As + chunk * 512), 16, 0, 0);
            __builtin_amdgcn_global_load_lds(
                (GV*)(Bt + (size_t)(n0 + row) * Kk + k0 + lcol),
                (LV*)(Bs + chunk * 512), 16, 0, 0);
        }
        __syncthreads();
        #pragma unroll
        for (int kk = 0; kk < 2; ++kk) {
            bf16x8 af[4], bfr[4];
            #pragma unroll
            for (int mi = 0; mi < 4; ++mi)
                af[mi] = *(const bf16x8*)&As[(wr * 64 + mi * 16 + lx) * 64 + kk * 32 + hi * 8];
            #pragma unroll
            for (int ni = 0; ni < 4; ++ni)
                bfr[ni] = *(const bf16x8*)&Bs[(wc * 64 + ni * 16 + lx) * 64 + kk * 32 + hi * 8];
            #pragma unroll
            for (int mi = 0; mi < 4; ++mi)
                #pragma unroll
                for (int ni = 0; ni < 4; ++ni)
                    acc[mi][ni] = __builtin_amdgcn_mfma_f32_16x16x32_bf16(
                        af[mi], bfr[ni], acc[mi][ni], 0, 0, 0);
        }
        __syncthreads();
    }
    #pragma unroll
    for (int mi = 0; mi < 4; ++mi)
        #pragma unroll
        for (int ni = 0; ni < 4; ++ni)
            #pragma unroll
            for (int r = 0; r < 4; ++r) {
                size_t idx = (size_t)(m0 + wr * 64 + mi * 16 + hi * 4 + r) * Nn
                           + n0 + wc * 64 + ni * 16 + lx;
                if constexpr (OUT_BF16) ((unsigned short*)Cc)[idx] = f2bf(acc[mi][ni][r]);
                else                    ((float*)Cc)[idx] = acc[mi][ni][r];
            }
}

// ------------------------------------------------------- memory token prep
__global__ __launch_bounds__(256) void mem_kernel(
    const float* __restrict__ mem_k, const float* __restrict__ mem_v,
    const float* __restrict__ vscal,
    unsigned short* __restrict__ kfull, unsigned short* __restrict__ vfull)
{
    const int bm = blockIdx.x;
    const int b = bm >> 6, mr = bm & 63;
    const int w = threadIdx.x >> 6, l = threadIdx.x & 63;
    const size_t src = ((size_t)mr * NKV + w) * HD + l;
    float kvv = mem_k[src];
    float ss = wave_sum(kvv * kvv);
    float scale = rsqrtf(ss * (1.f / 64.f) + EPS) * 1.2f;
    const size_t dst = ((size_t)(b * NKV + w) * S_TOT + mr) * 64 + l;
    kfull[dst] = f2bf(kvv * scale);
    vfull[dst] = f2bf(mem_v[src] * vscal[0]);
}

// -------------------------------------------------------- MFMA flash attn
// R11 VERBATIM (passed at absmax 5.9e-3).
struct AttnShared {
    unsigned short Ks[2][4096];   // [buf][row*64 + swz-col]      (K[s][d])
    unsigned short Vt[2][4096];   // [buf][row*64 + swz(sigma(s))] (V^T[d][q])
    unsigned short Ps[128 * 64];  // [row*64 + swz(q)]            (P[t][q])
};

__device__ __forceinline__ void attn_compute(
    const bool diag, const int trel, const int pbase,
    const int lx, const int hi, const int r7, const int cur,
    AttnShared* sh, const bf16x8 (&kb0)[4], const bf16x8 (&kb1)[4],
    const bf16x8 (&aq)[2],
    f32x4 (&o_acc)[4], float (&l_r)[4])
{
    // S = Q K^T - FIXED_MAX (shift folded into C-init)
    f32x4 s_acc[4];
    #pragma unroll
    for (int nt = 0; nt < 4; ++nt) {
        s_acc[nt] = (f32x4){-FIXED_MAX, -FIXED_MAX, -FIXED_MAX, -FIXED_MAX};
        s_acc[nt] = __builtin_amdgcn_mfma_f32_16x16x32_bf16(aq[0], kb0[nt], s_acc[nt], 0, 0, 0);
        s_acc[nt] = __builtin_amdgcn_mfma_f32_16x16x32_bf16(aq[1], kb1[nt], s_acc[nt], 0, 0, 0);
    }
    if (diag) {
        #pragma unroll
        for (int r = 0; r < 4; ++r) {
            const int thr = trel + r;
            #pragma unroll
            for (int nt = 0; nt < 4; ++nt)
                if (nt * 16 + lx > thr) s_acc[nt][r] = -INFINITY;
        }
    }
    // exp2 (bare v_exp_f32) + packed bf16 store: q-positions lx*4+nt
    #pragma unroll
    for (int r = 0; r < 4; ++r) {
        const int prow = pbase + hi * 4 + r;
        const float p0 = exp2_raw(s_acc[0][r]);
        const float p1 = exp2_raw(s_acc[1][r]);
        const float p2 = exp2_raw(s_acc[2][r]);
        const float p3 = exp2_raw(s_acc[3][r]);
        l_r[r] += (p0 + p1) + (p2 + p3);
        uint2 pk;
        pk.x = cvt_pk_bf16(p0, p1);
        pk.y = cvt_pk_bf16(p2, p3);
        const int idx = prow * 64 + ((((lx >> 1) ^ (prow & 7)) << 3) | ((lx & 1) << 2));
        *(uint2*)&sh->Ps[idx] = pk;   // 8B-aligned
    }
    // O += P V   (read addressing: group-XOR with r7)
    #pragma unroll
    for (int kk = 0; kk < 2; ++kk) {
        bf16x8 pa = *(const bf16x8*)&sh->Ps[(pbase + lx) * 64 + (((kk * 4 + hi) ^ r7) << 3)];
        #pragma unroll
        for (int dt = 0; dt < 4; ++dt) {
            bf16x8 vb = *(const bf16x8*)&sh->Vt[cur][(dt * 16 + lx) * 64 + (((kk * 4 + hi) ^ r7) << 3)];
            o_acc[dt] = __builtin_amdgcn_mfma_f32_16x16x32_bf16(pa, vb, o_acc[dt], 0, 0, 0);
        }
    }
}

__device__ __forceinline__ void attn_tile(
    const int st, const int nst, const int dtile, const int trel, const int pbase,
    const int w, const int lane, const int lx, const int hi,
    const unsigned short* __restrict__ kbase,
    const unsigned short* __restrict__ vbase,
    AttnShared* sh, ushort8& vn_c, ushort8& vn_n,
    const bf16x8 (&aq)[2],
    f32x4 (&o_acc)[4], float (&l_r)[4])
{
    const int cur = st & 1;
    const int r7 = lx & 7;
    // 1. write prefetched V (tile st) into Vt[cur] at sigma-permuted column
    const int q = (lane & 15) * 4 + (lane >> 4);   // sigma(s), s = lane
    #pragma unroll
    for (int j = 0; j < 8; ++j) {
        const int row = w * 8 + j;                 // d index (8 waves x 8 rows)
        sh->Vt[cur][row * 64 + ((((q >> 3) ^ (row & 7)) << 3) | (q & 7))] =
            (unsigned short)vn_c[j];
    }
    __syncthreads();   // drains K gload_lds for tile st; publishes Vt[cur]
    // 2. prefetch tile st+1 (8 waves x 8 rows = full 64-row K tile)
    if (st + 1 < nst) {
        const int s0n = (st + 1) * 64;
        const int swz = ((lane & 7) ^ (lane >> 3)) << 3;
        __builtin_amdgcn_global_load_lds(
            (GV*)(kbase + (size_t)(s0n + w * 8 + (lane >> 3)) * 64 + swz),
            (LV*)(&sh->Ks[cur ^ 1][w * 512]), 16, 0, 0);
        vn_n = *(const ushort8*)&vbase[(size_t)(s0n + lane) * 64 + w * 8];
    }
    if (st > dtile) return;   // fully masked for this wave: staging+barrier only
    // 3. K fragments (swizzled read)
    bf16x8 kb0[4], kb1[4];
    #pragma unroll
    for (int nt = 0; nt < 4; ++nt) {
        const int row = nt * 16 + lx;
        kb0[nt] = *(const bf16x8*)&sh->Ks[cur][row * 64 + ((hi ^ r7) << 3)];
        kb1[nt] = *(const bf16x8*)&sh->Ks[cur][row * 64 + (((4 + hi) ^ r7) << 3)];
    }
    // 4. compute this wave's q-tile
    attn_compute(st == dtile, trel, pbase, lx, hi, r7, cur, sh, kb0, kb1, aq, o_acc, l_r);
}

__global__ __launch_bounds__(512) void attn_kernel(
    const unsigned short* __restrict__ qh, const unsigned short* __restrict__ kf,
    const unsigned short* __restrict__ vf, unsigned short* __restrict__ y)
{
    __shared__ AttnShared sh;
    const int p = blockIdx.x;                  // pair index 0..15
    const int h = blockIdx.y, b = blockIdx.z;
    const int kv = h >> 2;
    const int jA = p, jB = 31 - p;
    const int tid = threadIdx.x, w = tid >> 6, lane = tid & 63;
    const int lx = lane & 15, hi = lane >> 4;
    const int qsel = w >> 2, wl = w & 3;       // waves 0-3: A, waves 4-7: B
    const int t0q = (qsel ? jB : jA) * 64;
    const int dtile = (qsel ? jB : jA) + 1;    // this wave's diagonal s-tile
    const int trel = 16 * wl + hi * 4;
    const int pbase = w * 16;

    bf16x8 aq[2];
    {
        const unsigned short* qp = qh + ((size_t)(b * NH + h) * T + t0q + 16 * wl + lx) * 64;
        aq[0] = *(const bf16x8*)&qp[hi * 8];
        aq[1] = *(const bf16x8*)&qp[32 + hi * 8];
    }
    f32x4 o_acc[4];
    float l_r[4];
    #pragma unroll
    for (int dt = 0; dt < 4; ++dt) o_acc[dt] = (f32x4){0.f, 0.f, 0.f, 0.f};
    #pragma unroll
    for (int r = 0; r < 4; ++r) l_r[r] = 0.f;

    const unsigned short* kbase = kf + (size_t)(b * NKV + kv) * S_TOT * 64;
    const unsigned short* vbase = vf + (size_t)(b * NKV + kv) * S_TOT * 64;

    const int nst = jB + 2;          // 18..33
    // prologue: stage K tile 0 -> Ks[0] (one call per wave); V tile 0 -> regs
    {
        const int swz = ((lane & 7) ^ (lane >> 3)) << 3;
        __builtin_amdgcn_global_load_lds(
            (GV*)(kbase + (size_t)(w * 8 + (lane >> 3)) * 64 + swz),
            (LV*)(&sh.Ks[0][w * 512]), 16, 0, 0);
    }
    ushort8 vnA, vnB;
    vnA = *(const ushort8*)&vbase[(size_t)lane * 64 + w * 8];
    for (int st = 0; st < nst; st += 2) {
        attn_tile(st, nst, dtile, trel, pbase, w, lane, lx, hi, kbase, vbase, &sh,
                  vnA, vnB, aq, o_acc, l_r);
        if (st + 1 < nst)
            attn_tile(st + 1, nst, dtile, trel, pbase, w, lane, lx, hi, kbase, vbase, &sh,
                      vnB, vnA, aq, o_acc, l_r);
    }

    // epilogue: l-reduce + write this wave's 16 rows
    float lt[4];
    #pragma unroll
    for (int r = 0; r < 4; ++r) {
        float v = l_r[r];
        #pragma unroll
        for (int off = 1; off < 16; off <<= 1) v += __shfl_xor(v, off, 64);
        lt[r] = 1.f / v;
    }
    #pragma unroll
    for (int dt = 0; dt < 4; ++dt)
        #pragma unroll
        for (int r = 0; r < 4; ++r) {
            int t = t0q + 16 * wl + hi * 4 + r;
            y[((size_t)(b * T) + t) * 1024 + h * 64 + dt * 16 + lx] =
                f2bf(o_acc[dt][r] * lt[r]);
        }
}

// ----------------------------------------------------------------- launcher
extern "C" void kernel_launch(void* const* d_in, const int* in_sizes, int n_in,
                              void* d_out, int out_size, void* d_ws, size_t ws_size,
                              hipStream_t stream)
{
    const float* x     = (const float*)d_in[0];
    const float* ve    = (const float*)d_in[1];
    const float* cosb  = (const float*)d_in[2];
    const float* sinb  = (const float*)d_in[3];
    const float* Wq    = (const float*)d_in[4];
    const float* Wk    = (const float*)d_in[5];
    const float* Wv    = (const float*)d_in[6];
    const float* Wproj = (const float*)d_in[7];
    const float* Wg    = (const float*)d_in[8];
    const float* memk  = (const float*)d_in[9];
    const float* memv  = (const float*)d_in[10];
    const float* vscal = (const float*)d_in[11];

    unsigned short* xh    = (unsigned short*)d_ws;
    unsigned short* wqkv  = xh + (size_t)4096 * 1024;
    unsigned short* wproj = wqkv + (size_t)1536 * 1024;
    unsigned short* qhb   = wproj + (size_t)1024 * 1024;
    unsigned short* kfull = qhb + (size_t)4096 * 1024;
    unsigned short* vfull = kfull + (size_t)B * NKV * S_TOT * 64;
    unsigned short* qkvb  = vfull + (size_t)B * NKV * S_TOT * 64;  // 4096x1536 bf16
    unsigned short* ybuf  = xh;   // alias: xh dead after QKV GEMM
    float* out = (float*)d_out;

    const dim3 blk(256);
    // one fused cast: x | Wq | Wk | Wv | Wproj -> contiguous bf16 region at ws
    cast_all<<<dim3(6656), blk, 0, stream>>>(x, Wq, Wk, Wv, Wproj, xh);

    qkv_gemm_raw<<<dim3(12, 64), blk, 0, stream>>>(xh, wqkv, qkvb);
    fuse_kernel<<<dim3(B * T), blk, 0, stream>>>(x, ve, cosb, sinb, Wg, qkvb,
                                                 qhb, kfull, vfull);
    mem_kernel<<<dim3(B * M), blk, 0, stream>>>(memk, memv, vscal, kfull, vfull);
    attn_kernel<<<dim3(16, NH, B), dim3(512), 0, stream>>>(qhb, kfull, vfull, ybuf);
    gemm_bf16<false><<<dim3(8, 32), blk, 0, stream>>>(ybuf, wproj, out, 1024, 1024);
}

// Round 15
// 102.779 us; speedup vs baseline: 1.9520x; 1.0797x over previous
//
#include <hip/hip_runtime.h>
#include <hip/hip_bf16.h>
#include <math.h>

#define B 2
#define T 2048
#define C 1024
#define NH 16
#define NKV 4
#define HD 64
#define M 64
#define GC 32
#define S_TOT (M + T)   // 2112
#define EPS 1e-6f
// |score| bound in exp2 domain: ||q||*||k|| = (8*0.2164)*(8*1.2) = 16.62
#define FIXED_MAX 17.0f

using bf16x8  = __attribute__((ext_vector_type(8))) __bf16;
using f32x4   = __attribute__((ext_vector_type(4))) float;
using ushort8 = __attribute__((ext_vector_type(8))) unsigned short;
using ushort4v= __attribute__((ext_vector_type(4))) unsigned short;

typedef __attribute__((address_space(1))) const void GV;
typedef __attribute__((address_space(3))) void LV;

__device__ inline unsigned short f2bf(float f) {
    __bf16 h = (__bf16)f;
    return __builtin_bit_cast(unsigned short, h);
}
__device__ inline float bf2f(unsigned short u) {
    unsigned int x = (unsigned int)u << 16;
    return __builtin_bit_cast(float, x);
}
__device__ inline float wave_sum(float v) {
    #pragma unroll
    for (int off = 32; off; off >>= 1) v += __shfl_xor(v, off, 64);
    return v;
}
__device__ __forceinline__ float exp2_raw(float x) {
    float y;
    asm("v_exp_f32 %0, %1" : "=v"(y) : "v"(x));
    return y;
}
__device__ __forceinline__ unsigned int cvt_pk_bf16(float lo, float hi) {
    unsigned int u;
    asm("v_cvt_pk_bf16_f32 %0, %1, %2" : "=v"(u) : "v"(lo), "v"(hi));
    return u;
}

// ----------------------------------------- fused fp32 -> bf16 (all 5 inputs)
__global__ __launch_bounds__(256) void cast_all(
    const float* __restrict__ s0, const float* __restrict__ s1,
    const float* __restrict__ s2, const float* __restrict__ s3,
    const float* __restrict__ s4, unsigned short* __restrict__ dst)
{
    const int i = blockIdx.x * 256 + threadIdx.x;   // float4 index, 1703936 total
    const float* src; int off;
    if      (i < 1048576) { src = s0; off = i; }
    else if (i < 1310720) { src = s1; off = i - 1048576; }
    else if (i < 1376256) { src = s2; off = i - 1310720; }
    else if (i < 1441792) { src = s3; off = i - 1376256; }
    else                  { src = s4; off = i - 1441792; }
    float4 v = ((const float4*)src)[off];
    ushort4v o;
    o.x = f2bf(v.x); o.y = f2bf(v.y); o.z = f2bf(v.z); o.w = f2bf(v.w);
    ((ushort4v*)dst)[i] = o;
}

// --------------------------- QKV GEMM, BM=64 core, RAW bf16 output (verified)
__global__ __launch_bounds__(256) void qkv_gemm_raw(
    const unsigned short* __restrict__ A, const unsigned short* __restrict__ Bt,
    unsigned short* __restrict__ Cc)
{
    __shared__ unsigned short As[64 * 64];
    __shared__ unsigned short Bs[128 * 64];
    const int tid = threadIdx.x;
    const int w = tid >> 6, lane = tid & 63, lx = lane & 15, hi = lane >> 4;
    const int wr = w >> 1, wc = w & 1;
    const int m0 = blockIdx.y * 64, n0 = blockIdx.x * 128;
    const int lrow = lane >> 3;
    const int lcol = (lane & 7) * 8;

    f32x4 acc[2][4];
    #pragma unroll
    for (int mi = 0; mi < 2; ++mi)
        #pragma unroll
        for (int ni = 0; ni < 4; ++ni) acc[mi][ni] = (f32x4){0.f, 0.f, 0.f, 0.f};

    for (int k0 = 0; k0 < 1024; k0 += 64) {
        #pragma unroll
        for (int p = 0; p < 2; ++p) {           // A: 8 chunks, 2/wave
            const int chunk = w * 2 + p;
            __builtin_amdgcn_global_load_lds(
                (GV*)(A + (size_t)(m0 + chunk * 8 + lrow) * 1024 + k0 + lcol),
                (LV*)(As + chunk * 512), 16, 0, 0);
        }
        #pragma unroll
        for (int p = 0; p < 4; ++p) {           // B: 16 chunks, 4/wave
            const int chunk = w * 4 + p;
            __builtin_amdgcn_global_load_lds(
                (GV*)(Bt + (size_t)(n0 + chunk * 8 + lrow) * 1024 + k0 + lcol),
                (LV*)(Bs + chunk * 512), 16, 0, 0);
        }
        __syncthreads();
        #pragma unroll
        for (int kk = 0; kk < 2; ++kk) {
            bf16x8 af[2], bfr[4];
            #pragma unroll
            for (int mi = 0; mi < 2; ++mi)
                af[mi] = *(const bf16x8*)&As[(wr * 32 + mi * 16 + lx) * 64 + kk * 32 + hi * 8];
            #pragma unroll
            for (int ni = 0; ni < 4; ++ni)
                bfr[ni] = *(const bf16x8*)&Bs[(wc * 64 + ni * 16 + lx) * 64 + kk * 32 + hi * 8];
            #pragma unroll
            for (int mi = 0; mi < 2; ++mi)
                #pragma unroll
                for (int ni = 0; ni < 4; ++ni)
                    acc[mi][ni] = __builtin_amdgcn_mfma_f32_16x16x32_bf16(
                        af[mi], bfr[ni], acc[mi][ni], 0, 0, 0);
        }
        __syncthreads();
    }
    #pragma unroll
    for (int mi = 0; mi < 2; ++mi)
        #pragma unroll
        for (int ni = 0; ni < 4; ++ni)
            #pragma unroll
            for (int r = 0; r < 4; ++r)
                Cc[(size_t)(m0 + wr * 32 + mi * 16 + hi * 4 + r) * 1536
                   + n0 + wc * 64 + ni * 16 + lx] = f2bf(acc[mi][ni][r]);
}

// --------------------------- proj GEMM, BM=128 x BN=64 (512 blocks = 2/CU)
__global__ __launch_bounds__(256) void gemm_proj(
    const unsigned short* __restrict__ A, const unsigned short* __restrict__ Bt,
    float* __restrict__ Cc)
{
    __shared__ unsigned short As[128 * 64];
    __shared__ unsigned short Bs[64 * 64];
    const int tid = threadIdx.x;
    const int w = tid >> 6, lane = tid & 63, lx = lane & 15, hi = lane >> 4;
    const int wr = w >> 1, wc = w & 1;
    const int m0 = blockIdx.y * 128, n0 = blockIdx.x * 64;
    const int lrow = lane >> 3;
    const int lcol = (lane & 7) * 8;

    f32x4 acc[4][2];
    #pragma unroll
    for (int mi = 0; mi < 4; ++mi)
        #pragma unroll
        for (int ni = 0; ni < 2; ++ni) acc[mi][ni] = (f32x4){0.f, 0.f, 0.f, 0.f};

    for (int k0 = 0; k0 < 1024; k0 += 64) {
        #pragma unroll
        for (int p = 0; p < 4; ++p) {           // A: 16 chunks, 4/wave
            const int chunk = w * 4 + p;
            __builtin_amdgcn_global_load_lds(
                (GV*)(A + (size_t)(m0 + chunk * 8 + lrow) * 1024 + k0 + lcol),
                (LV*)(As + chunk * 512), 16, 0, 0);
        }
        #pragma unroll
        for (int p = 0; p < 2; ++p) {           // B: 8 chunks, 2/wave
            const int chunk = w * 2 + p;
            __builtin_amdgcn_global_load_lds(
                (GV*)(Bt + (size_t)(n0 + chunk * 8 + lrow) * 1024 + k0 + lcol),
                (LV*)(Bs + chunk * 512), 16, 0, 0);
        }
        __syncthreads();
        #pragma unroll
        for (int kk = 0; kk < 2; ++kk) {
            bf16x8 af[4], bfr[2];
            #pragma unroll
            for (int mi = 0; mi < 4; ++mi)
                af[mi] = *(const bf16x8*)&As[(wr * 64 + mi * 16 + lx) * 64 + kk * 32 + hi * 8];
            #pragma unroll
            for (int ni = 0; ni < 2; ++ni)
                bfr[ni] = *(const bf16x8*)&Bs[(wc * 32 + ni * 16 + lx) * 64 + kk * 32 + hi * 8];
            #pragma unroll
            for (int mi = 0; mi < 4; ++mi)
                #pragma unroll
                for (int ni = 0; ni < 2; ++ni)
                    acc[mi][ni] = __builtin_amdgcn_mfma_f32_16x16x32_bf16(
                        af[mi], bfr[ni], acc[mi][ni], 0, 0, 0);
        }
        __syncthreads();
    }
    #pragma unroll
    for (int mi = 0; mi < 4; ++mi)
        #pragma unroll
        for (int ni = 0; ni < 2; ++ni)
            #pragma unroll
            for (int r = 0; r < 4; ++r)
                Cc[(size_t)(m0 + wr * 64 + mi * 16 + hi * 4 + r) * 1024
                   + n0 + wc * 32 + ni * 16 + lx] = acc[mi][ni][r];
}

// ------------------------------------------------- gate + RoPE + RMS fusion
// Loads halved via shfl partner exchange; mem-token prep merged (blocks 0..127).
__global__ __launch_bounds__(256) void fuse_kernel(
    const float* __restrict__ x, const float* __restrict__ ve,
    const float* __restrict__ cosb, const float* __restrict__ sinb,
    const float* __restrict__ Wg, const unsigned short* __restrict__ qkv,
    const float* __restrict__ mem_k, const float* __restrict__ mem_v,
    const float* __restrict__ vscal,
    unsigned short* __restrict__ qh, unsigned short* __restrict__ kfull,
    unsigned short* __restrict__ vfull)
{
    const int bt = blockIdx.x;
    const int b = bt >> 11, t = bt & (T - 1);
    const int w = threadIdx.x >> 6, l = threadIdx.x & 63, i = l & 31;
    const float c = cosb[t * 32 + i];
    const float s = sinb[t * 32 + i];
    const unsigned short* row = qkv + (size_t)bt * 1536;

    #pragma unroll
    for (int hq = 0; hq < 4; ++hq) {
        const int h = w + hq * 4;
        float own = bf2f(row[h * 64 + l]);
        float part = __shfl_xor(own, 32, 64);
        float val = (l < 32) ? (own * c - part * s) : (part * s + own * c);
        float ss = wave_sum(val * val);
        float scale = rsqrtf(ss * (1.f / 64.f) + EPS) * 0.21640426f;
        qh[((size_t)(b * NH + h) * T + t) * 64 + l] = f2bf(val * scale);
    }
    {
        float own = bf2f(row[1024 + w * 64 + l]);
        float part = __shfl_xor(own, 32, 64);
        float val = (l < 32) ? (own * c - part * s) : (part * s + own * c);
        float ss = wave_sum(val * val);
        float scale = rsqrtf(ss * (1.f / 64.f) + EPS) * 1.2f;
        kfull[((size_t)(b * NKV + w) * S_TOT + M + t) * 64 + l] = f2bf(val * scale);
    }
    {
        const float* xr = x + (size_t)bt * 1024;
        float g = 0.f;
        #pragma unroll
        for (int gi = 0; gi < GC; ++gi) g += xr[gi] * Wg[w * GC + gi];
        g = 3.f / (1.f + __expf(-g));
        float vv = bf2f(row[1280 + w * 64 + l]) + g * ve[(size_t)bt * 256 + w * 64 + l];
        vfull[((size_t)(b * NKV + w) * S_TOT + M + t) * 64 + l] = f2bf(vv);
    }
    // merged memory-token prep (was mem_kernel): blocks 0..B*M-1
    if (bt < B * M) {
        const int b2 = bt >> 6, mr = bt & 63;
        const size_t src = ((size_t)mr * NKV + w) * HD + l;
        float kvv = mem_k[src];
        float ss = wave_sum(kvv * kvv);
        float scale = rsqrtf(ss * (1.f / 64.f) + EPS) * 1.2f;
        const size_t dst = ((size_t)(b2 * NKV + w) * S_TOT + mr) * 64 + l;
        kfull[dst] = f2bf(kvv * scale);
        vfull[dst] = f2bf(mem_v[src] * vscal[0]);
    }
}

// -------------------------------------------------------- MFMA flash attn
// R11/R14 structure + s_setprio around MFMA clusters (T5, exonerated by bisect).
struct AttnShared {
    unsigned short Ks[2][4096];   // [buf][row*64 + swz-col]      (K[s][d])
    unsigned short Vt[2][4096];   // [buf][row*64 + swz(sigma(s))] (V^T[d][q])
    unsigned short Ps[128 * 64];  // [row*64 + swz(q)]            (P[t][q])
};

__device__ __forceinline__ void attn_compute(
    const bool diag, const int trel, const int pbase,
    const int lx, const int hi, const int r7, const int cur,
    AttnShared* sh, const bf16x8 (&kb0)[4], const bf16x8 (&kb1)[4],
    const bf16x8 (&aq)[2],
    f32x4 (&o_acc)[4], float (&l_r)[4])
{
    // S = Q K^T - FIXED_MAX (shift folded into C-init)
    f32x4 s_acc[4];
    __builtin_amdgcn_s_setprio(1);
    #pragma unroll
    for (int nt = 0; nt < 4; ++nt) {
        s_acc[nt] = (f32x4){-FIXED_MAX, -FIXED_MAX, -FIXED_MAX, -FIXED_MAX};
        s_acc[nt] = __builtin_amdgcn_mfma_f32_16x16x32_bf16(aq[0], kb0[nt], s_acc[nt], 0, 0, 0);
        s_acc[nt] = __builtin_amdgcn_mfma_f32_16x16x32_bf16(aq[1], kb1[nt], s_acc[nt], 0, 0, 0);
    }
    __builtin_amdgcn_s_setprio(0);
    if (diag) {
        #pragma unroll
        for (int r = 0; r < 4; ++r) {
            const int thr = trel + r;
            #pragma unroll
            for (int nt = 0; nt < 4; ++nt)
                if (nt * 16 + lx > thr) s_acc[nt][r] = -INFINITY;
        }
    }
    // exp2 (bare v_exp_f32) + packed bf16 store: q-positions lx*4+nt
    #pragma unroll
    for (int r = 0; r < 4; ++r) {
        const int prow = pbase + hi * 4 + r;
        const float p0 = exp2_raw(s_acc[0][r]);
        const float p1 = exp2_raw(s_acc[1][r]);
        const float p2 = exp2_raw(s_acc[2][r]);
        const float p3 = exp2_raw(s_acc[3][r]);
        l_r[r] += (p0 + p1) + (p2 + p3);
        uint2 pk;
        pk.x = cvt_pk_bf16(p0, p1);
        pk.y = cvt_pk_bf16(p2, p3);
        const int idx = prow * 64 + ((((lx >> 1) ^ (prow & 7)) << 3) | ((lx & 1) << 2));
        *(uint2*)&sh->Ps[idx] = pk;   // 8B-aligned
    }
    // O += P V   (read addressing: group-XOR with r7)
    __builtin_amdgcn_s_setprio(1);
    #pragma unroll
    for (int kk = 0; kk < 2; ++kk) {
        bf16x8 pa = *(const bf16x8*)&sh->Ps[(pbase + lx) * 64 + (((kk * 4 + hi) ^ r7) << 3)];
        #pragma unroll
        for (int dt = 0; dt < 4; ++dt) {
            bf16x8 vb = *(const bf16x8*)&sh->Vt[cur][(dt * 16 + lx) * 64 + (((kk * 4 + hi) ^ r7) << 3)];
            o_acc[dt] = __builtin_amdgcn_mfma_f32_16x16x32_bf16(pa, vb, o_acc[dt], 0, 0, 0);
        }
    }
    __builtin_amdgcn_s_setprio(0);
}

__device__ __forceinline__ void attn_tile(
    const int st, const int nst, const int dtile, const int trel, const int pbase,
    const int w, const int lane, const int lx, const int hi,
    const unsigned short* __restrict__ kbase,
    const unsigned short* __restrict__ vbase,
    AttnShared* sh, ushort8& vn_c, ushort8& vn_n,
    const bf16x8 (&aq)[2],
    f32x4 (&o_acc)[4], float (&l_r)[4])
{
    const int cur = st & 1;
    const int r7 = lx & 7;
    // 1. write prefetched V (tile st) into Vt[cur] at sigma-permuted column
    const int q = (lane & 15) * 4 + (lane >> 4);   // sigma(s), s = lane
    #pragma unroll
    for (int j = 0; j < 8; ++j) {
        const int row = w * 8 + j;                 // d index (8 waves x 8 rows)
        sh->Vt[cur][row * 64 + ((((q >> 3) ^ (row & 7)) << 3) | (q & 7))] =
            (unsigned short)vn_c[j];
    }
    __syncthreads();   // drains K gload_lds for tile st; publishes Vt[cur]
    // 2. prefetch tile st+1 (8 waves x 8 rows = full 64-row K tile)
    if (st + 1 < nst) {
        const int s0n = (st + 1) * 64;
        const int swz = ((lane & 7) ^ (lane >> 3)) << 3;
        __builtin_amdgcn_global_load_lds(
            (GV*)(kbase + (size_t)(s0n + w * 8 + (lane >> 3)) * 64 + swz),
            (LV*)(&sh->Ks[cur ^ 1][w * 512]), 16, 0, 0);
        vn_n = *(const ushort8*)&vbase[(size_t)(s0n + lane) * 64 + w * 8];
    }
    if (st > dtile) return;   // fully masked for this wave: staging+barrier only
    // 3. K fragments (swizzled read)
    bf16x8 kb0[4], kb1[4];
    #pragma unroll
    for (int nt = 0; nt < 4; ++nt) {
        const int row = nt * 16 + lx;
        kb0[nt] = *(const bf16x8*)&sh->Ks[cur][row * 64 + ((hi ^ r7) << 3)];
        kb1[nt] = *(const bf16x8*)&sh->Ks[cur][row * 64 + (((4 + hi) ^ r7) << 3)];
    }
    // 4. compute this wave's q-tile
    attn_compute(st == dtile, trel, pbase, lx, hi, r7, cur, sh, kb0, kb1, aq, o_acc, l_r);
}

__global__ __launch_bounds__(512) void attn_kernel(
    const unsigned short* __restrict__ qh, const unsigned short* __restrict__ kf,
    const unsigned short* __restrict__ vf, unsigned short* __restrict__ y)
{
    __shared__ AttnShared sh;
    const int p = blockIdx.x;                  // pair index 0..15
    const int h = blockIdx.y, b = blockIdx.z;
    const int kv = h >> 2;
    const int jA = p, jB = 31 - p;
    const int tid = threadIdx.x, w = tid >> 6, lane = tid & 63;
    const int lx = lane & 15, hi = lane >> 4;
    const int qsel = w >> 2, wl = w & 3;       // waves 0-3: A, waves 4-7: B
    const int t0q = (qsel ? jB : jA) * 64;
    const int dtile = (qsel ? jB : jA) + 1;    // this wave's diagonal s-tile
    const int trel = 16 * wl + hi * 4;
    const int pbase = w * 16;

    bf16x8 aq[2];
    {
        const unsigned short* qp = qh + ((size_t)(b * NH + h) * T + t0q + 16 * wl + lx) * 64;
        aq[0] = *(const bf16x8*)&qp[hi * 8];
        aq[1] = *(const bf16x8*)&qp[32 + hi * 8];
    }
    f32x4 o_acc[4];
    float l_r[4];
    #pragma unroll
    for (int dt = 0; dt < 4; ++dt) o_acc[dt] = (f32x4){0.f, 0.f, 0.f, 0.f};
    #pragma unroll
    for (int r = 0; r < 4; ++r) l_r[r] = 0.f;

    const unsigned short* kbase = kf + (size_t)(b * NKV + kv) * S_TOT * 64;
    const unsigned short* vbase = vf + (size_t)(b * NKV + kv) * S_TOT * 64;

    const int nst = jB + 2;          // 18..33
    // prologue: stage K tile 0 -> Ks[0] (one call per wave); V tile 0 -> regs
    {
        const int swz = ((lane & 7) ^ (lane >> 3)) << 3;
        __builtin_amdgcn_global_load_lds(
            (GV*)(kbase + (size_t)(w * 8 + (lane >> 3)) * 64 + swz),
            (LV*)(&sh.Ks[0][w * 512]), 16, 0, 0);
    }
    ushort8 vnA, vnB;
    vnA = *(const ushort8*)&vbase[(size_t)lane * 64 + w * 8];
    for (int st = 0; st < nst; st += 2) {
        attn_tile(st, nst, dtile, trel, pbase, w, lane, lx, hi, kbase, vbase, &sh,
                  vnA, vnB, aq, o_acc, l_r);
        if (st + 1 < nst)
            attn_tile(st + 1, nst, dtile, trel, pbase, w, lane, lx, hi, kbase, vbase, &sh,
                      vnB, vnA, aq, o_acc, l_r);
    }

    // epilogue: l-reduce + write this wave's 16 rows
    float lt[4];
    #pragma unroll
    for (int r = 0; r < 4; ++r) {
        float v = l_r[r];
        #pragma unroll
        for (int off = 1; off < 16; off <<= 1) v += __shfl_xor(v, off, 64);
        lt[r] = 1.f / v;
    }
    #pragma unroll
    for (int dt = 0; dt < 4; ++dt)
        #pragma unroll
        for (int r = 0; r < 4; ++r) {
            int t = t0q + 16 * wl + hi * 4 + r;
            y[((size_t)(b * T) + t) * 1024 + h * 64 + dt * 16 + lx] =
                f2bf(o_acc[dt][r] * lt[r]);
        }
}

// ----------------------------------------------------------------- launcher
extern "C" void kernel_launch(void* const* d_in, const int* in_sizes, int n_in,
                              void* d_out, int out_size, void* d_ws, size_t ws_size,
                              hipStream_t stream)
{
    const float* x     = (const float*)d_in[0];
    const float* ve    = (const float*)d_in[1];
    const float* cosb  = (const float*)d_in[2];
    const float* sinb  = (const float*)d_in[3];
    const float* Wq    = (const float*)d_in[4];
    const float* Wk    = (const float*)d_in[5];
    const float* Wv    = (const float*)d_in[6];
    const float* Wproj = (const float*)d_in[7];
    const float* Wg    = (const float*)d_in[8];
    const float* memk  = (const float*)d_in[9];
    const float* memv  = (const float*)d_in[10];
    const float* vscal = (const float*)d_in[11];

    unsigned short* xh    = (unsigned short*)d_ws;
    unsigned short* wqkv  = xh + (size_t)4096 * 1024;
    unsigned short* wproj = wqkv + (size_t)1536 * 1024;
    unsigned short* qhb   = wproj + (size_t)1024 * 1024;
    unsigned short* kfull = qhb + (size_t)4096 * 1024;
    unsigned short* vfull = kfull + (size_t)B * NKV * S_TOT * 64;
    unsigned short* qkvb  = vfull + (size_t)B * NKV * S_TOT * 64;  // 4096x1536 bf16
    unsigned short* ybuf  = xh;   // alias: xh dead after QKV GEMM
    float* out = (float*)d_out;

    const dim3 blk(256);
    // one fused cast: x | Wq | Wk | Wv | Wproj -> contiguous bf16 region at ws
    cast_all<<<dim3(6656), blk, 0, stream>>>(x, Wq, Wk, Wv, Wproj, xh);

    qkv_gemm_raw<<<dim3(12, 64), blk, 0, stream>>>(xh, wqkv, qkvb);
    fuse_kernel<<<dim3(B * T), blk, 0, stream>>>(x, ve, cosb, sinb, Wg, qkvb,
                                                 memk, memv, vscal,
                                                 qhb, kfull, vfull);
    attn_kernel<<<dim3(16, NH, B), dim3(512), 0, stream>>>(qhb, kfull, vfull, ybuf);
    gemm_proj<<<dim3(16, 32), blk, 0, stream>>>(ybuf, wproj, out);
}